// Round 1
// baseline (332.308 us; speedup 1.0000x reference)
//
#include <hip/hip_runtime.h>
#include <hip/hip_bf16.h>

// SpatialLinearAttention: b=2,f=16,h=w=64,c=256, heads=8, D=32
// BF=32 fused batch, n=4096, hD=256.
// out[n,c] = sum_hd softmax_d(xWq)[n,hd] * W2[hd,c]
// W2[hd,c] = sum_e (ctx[h,d,e]/den[h,d]) * Wo[h*32+e,c]
// ctx[h,d,e] = sum_n exp(xWk)[n,h*32+d] * (xWv)[n,h*32+e];  den = sum_n exp(xWk)

typedef __attribute__((ext_vector_type(8))) short bf16x8;
typedef __attribute__((ext_vector_type(4))) float f32x4;

__device__ __forceinline__ unsigned short f2bf(float x) {
  union { float f; unsigned u; } c; c.f = x;
  unsigned r = (c.u + 0x7FFFu + ((c.u >> 16) & 1u)) >> 16;  // RNE
  return (unsigned short)r;
}

// ---------------- K0: transpose & convert weights to [N][K] bf16 ----------------
__global__ __launch_bounds__(256) void k0_prep(const float* __restrict__ Wq,
                                               const float* __restrict__ Wk,
                                               const float* __restrict__ Wv,
                                               unsigned short* __restrict__ WqT,
                                               unsigned short* __restrict__ WkvT) {
  int r = blockIdx.x, c = threadIdx.x;
  if (r < 256)      WqT [(r      )*256 + c] = f2bf(Wq[c*256 + r]);
  else if (r < 512) WkvT[(r - 256)*256 + c] = f2bf(Wk[c*256 + (r-256)]);
  else              WkvT[(r - 256)*256 + c] = f2bf(Wv[c*256 + (r-512)]);
}

// ---------------- K1: kv projection GEMM, epilogue exp() for k ----------------
// C[131072][512] = x(f32,[M][256]) @ WkvT^T ; cols 0..255 -> Ek=exp(.), 256..511 -> V
__global__ __launch_bounds__(256) void k1_kvproj(const float* __restrict__ x,
                                                 const unsigned short* __restrict__ WkvT,
                                                 unsigned short* __restrict__ Ek,
                                                 unsigned short* __restrict__ Vb) {
  __shared__ unsigned short As[128*64];   // [m][k] bf16
  __shared__ unsigned short Bs[128*64];   // [n][k] bf16
  // XCD-bijective swizzle (grid 4096 = 8*512): keep the 4 N-tiles of one A-strip on one XCD
  int orig = blockIdx.x;
  int bid  = ((orig & 7) << 9) | (orig >> 3);
  int mt = bid >> 2, nt = bid & 3;
  int mbase = mt * 128, nbase = nt * 128;
  int tid = threadIdx.x;
  int lane = tid & 63, wid = tid >> 6;
  int wr = wid >> 1, wc = wid & 1;
  int cl = lane & 15, rq = (lane >> 4) << 2;
  f32x4 acc[4][4] = {};
  for (int k0 = 0; k0 < 256; k0 += 64) {
    // stage A: 128x64 f32 -> bf16 (reg-staged convert)
#pragma unroll
    for (int i = 0; i < 8; ++i) {
      int f = i*256 + tid;                 // 2048 float4
      int row = f >> 4, c4 = (f & 15) << 2;
      float4 v = *(const float4*)(x + (size_t)(mbase + row)*256 + k0 + c4);
      ushort4 u; u.x = f2bf(v.x); u.y = f2bf(v.y); u.z = f2bf(v.z); u.w = f2bf(v.w);
      *(ushort4*)(&As[row*64 + c4]) = u;
    }
    // stage B: 128x64 bf16 (already bf16)
#pragma unroll
    for (int i = 0; i < 4; ++i) {
      int e8 = i*256 + tid;                // 1024 chunks of 8
      int n = e8 >> 3, k8 = (e8 & 7) << 3;
      *(int4*)(&Bs[n*64 + k8]) = *(const int4*)(WkvT + (size_t)(nbase + n)*256 + k0 + k8);
    }
    __syncthreads();
#pragma unroll
    for (int ks = 0; ks < 64; ks += 32) {
      int ko = ks + ((lane >> 4) << 3);
      bf16x8 a[4], b[4];
#pragma unroll
      for (int mi = 0; mi < 4; ++mi) a[mi] = *(const bf16x8*)(&As[(wr*64 + mi*16 + cl)*64 + ko]);
#pragma unroll
      for (int ni = 0; ni < 4; ++ni) b[ni] = *(const bf16x8*)(&Bs[(wc*64 + ni*16 + cl)*64 + ko]);
#pragma unroll
      for (int mi = 0; mi < 4; ++mi)
#pragma unroll
        for (int ni = 0; ni < 4; ++ni)
          acc[mi][ni] = __builtin_amdgcn_mfma_f32_16x16x32_bf16(a[mi], b[ni], acc[mi][ni], 0, 0, 0);
    }
    __syncthreads();
  }
#pragma unroll
  for (int mi = 0; mi < 4; ++mi)
#pragma unroll
    for (int ni = 0; ni < 4; ++ni) {
      int col = nbase + wc*64 + ni*16 + cl;
#pragma unroll
      for (int r = 0; r < 4; ++r) {
        int row = mbase + wr*64 + mi*16 + rq + r;
        float v = acc[mi][ni][r];
        if (col < 256) Ek[(size_t)row*256 + col]       = f2bf(__expf(v));
        else           Vb[(size_t)row*256 + col - 256] = f2bf(v);
      }
    }
}

// ---------------- K2a: context partials ctx[bf][h][d][e] (+den at e=32) ----------------
__global__ __launch_bounds__(256) void k2a_ctx(const unsigned short* __restrict__ Ek,
                                               const unsigned short* __restrict__ Vb,
                                               float* __restrict__ ctx) {
  __shared__ float ekf[128*32];
  __shared__ float vf [128*32];
  __shared__ float clds[32*33];
  int bid = blockIdx.x;                    // (bf*8 + h)*4 + s
  int s = bid & 3, h = (bid >> 2) & 7, bfi = bid >> 5;
  int tid = threadIdx.x;
  for (int i = tid; i < 32*33; i += 256) clds[i] = 0.f;
  int p = tid & 31, ss = tid >> 5;
  int d0 = (p & 7) << 2;                   // d quad
  int e0 = (p >> 3) << 3;                  // e oct
  float acc[4][8] = {};
  float den[4] = {};
  size_t rowbase = (size_t)bfi*4096 + (size_t)s*1024;
  int nn = tid >> 1, hf = tid & 1;
  for (int ch = 0; ch < 8; ++ch) {
    __syncthreads();                       // protect LDS from previous chunk's readers
    {
      size_t g = (rowbase + ch*128 + nn) * 256 + h*32 + hf*16;
      int4 a0 = *(const int4*)(Ek + g);
      int4 a1 = *(const int4*)(Ek + g + 8);
      int4 b0 = *(const int4*)(Vb + g);
      int4 b1 = *(const int4*)(Vb + g + 8);
      unsigned* pu;
      float t[16];
      pu = (unsigned*)&a0;
#pragma unroll
      for (int i = 0; i < 4; ++i) { union{unsigned u; float f;} lo, hi; lo.u = pu[i] << 16; hi.u = pu[i] & 0xFFFF0000u; t[2*i] = lo.f; t[2*i+1] = hi.f; }
      pu = (unsigned*)&a1;
#pragma unroll
      for (int i = 0; i < 4; ++i) { union{unsigned u; float f;} lo, hi; lo.u = pu[i] << 16; hi.u = pu[i] & 0xFFFF0000u; t[8+2*i] = lo.f; t[8+2*i+1] = hi.f; }
#pragma unroll
      for (int i = 0; i < 4; ++i)
        *(float4*)(&ekf[nn*32 + hf*16 + 4*i]) = make_float4(t[4*i], t[4*i+1], t[4*i+2], t[4*i+3]);
      pu = (unsigned*)&b0;
#pragma unroll
      for (int i = 0; i < 4; ++i) { union{unsigned u; float f;} lo, hi; lo.u = pu[i] << 16; hi.u = pu[i] & 0xFFFF0000u; t[2*i] = lo.f; t[2*i+1] = hi.f; }
      pu = (unsigned*)&b1;
#pragma unroll
      for (int i = 0; i < 4; ++i) { union{unsigned u; float f;} lo, hi; lo.u = pu[i] << 16; hi.u = pu[i] & 0xFFFF0000u; t[8+2*i] = lo.f; t[8+2*i+1] = hi.f; }
#pragma unroll
      for (int i = 0; i < 4; ++i)
        *(float4*)(&vf[nn*32 + hf*16 + 4*i]) = make_float4(t[4*i], t[4*i+1], t[4*i+2], t[4*i+3]);
    }
    __syncthreads();
#pragma unroll 4
    for (int rr = 0; rr < 16; ++rr) {
      int n2 = ss*16 + rr;
      float4 e4 = *(const float4*)(&ekf[n2*32 + d0]);
      float4 v0 = *(const float4*)(&vf [n2*32 + e0]);
      float4 v1 = *(const float4*)(&vf [n2*32 + e0 + 4]);
#pragma unroll
      for (int i = 0; i < 4; ++i) {
        float e = ((float*)&e4)[i];
        acc[i][0] += e * v0.x; acc[i][1] += e * v0.y; acc[i][2] += e * v0.z; acc[i][3] += e * v0.w;
        acc[i][4] += e * v1.x; acc[i][5] += e * v1.y; acc[i][6] += e * v1.z; acc[i][7] += e * v1.w;
        den[i] += e;
      }
    }
  }
#pragma unroll
  for (int i = 0; i < 4; ++i) {
#pragma unroll
    for (int j = 0; j < 8; ++j) atomicAdd(&clds[(d0 + i)*33 + e0 + j], acc[i][j]);
    if (e0 == 0) atomicAdd(&clds[(d0 + i)*33 + 32], den[i]);
  }
  __syncthreads();
  float* g = ctx + ((size_t)bfi*8 + h)*(32*33);
  for (int i = tid; i < 32*33; i += 256) atomicAdd(&g[i], clds[i]);
}

// ---------------- K2b: W2t[bf][c][hd] = sum_e (ctx/den) * Wo ----------------
__global__ __launch_bounds__(256) void k2b_w2(const float* __restrict__ ctx,
                                              const float* __restrict__ Wo,
                                              unsigned short* __restrict__ W2t) {
  __shared__ float clds[32*33];
  int bid = blockIdx.x;                    // bf*8 + h
  int h = bid & 7, bfi = bid >> 3;
  int tid = threadIdx.x;                   // = c
  const float* g = ctx + (size_t)bid*(32*33);
  for (int i = tid; i < 32*33; i += 256) clds[i] = g[i];
  __syncthreads();
  float acc[32] = {};
#pragma unroll 4
  for (int e = 0; e < 32; ++e) {
    float w = Wo[(size_t)(h*32 + e)*256 + tid];
#pragma unroll
    for (int d = 0; d < 32; ++d) acc[d] += clds[d*33 + e] * w;
  }
  unsigned short* o = W2t + ((size_t)bfi*256 + tid)*256 + h*32;
#pragma unroll
  for (int d = 0; d < 32; ++d) o[d] = f2bf(acc[d] / clds[d*33 + 32]);
}

// ---------------- K3: fused q-proj -> softmax_d -> @W2t -> out ----------------
__global__ __launch_bounds__(256) void k3_fused(const float* __restrict__ x,
                                                const unsigned short* __restrict__ WqT,
                                                const unsigned short* __restrict__ W2t,
                                                float* __restrict__ out) {
  __shared__ unsigned short As[64*64];     // x strip bf16
  __shared__ unsigned short Bs[256*64];    // weight K-panel [n][k]
  __shared__ unsigned short Qs[64*256];    // softmaxed q strip [row][hd]
  int bid = blockIdx.x;
  int rowbase = bid * 64;
  int bfi = bid >> 6;
  int tid = threadIdx.x;
  int lane = tid & 63, wid = tid >> 6;     // wave owns 64-col strip
  int cl = lane & 15, rq = (lane >> 4) << 2;
  f32x4 acc[4][4] = {};
  // ---- phase 1: C1[64][256] = x @ WqT^T ----
  for (int k0 = 0; k0 < 256; k0 += 64) {
#pragma unroll
    for (int i = 0; i < 4; ++i) {
      int f = i*256 + tid;                 // 1024 float4
      int row = f >> 4, c4 = (f & 15) << 2;
      float4 v = *(const float4*)(x + (size_t)(rowbase + row)*256 + k0 + c4);
      ushort4 u; u.x = f2bf(v.x); u.y = f2bf(v.y); u.z = f2bf(v.z); u.w = f2bf(v.w);
      *(ushort4*)(&As[row*64 + c4]) = u;
    }
#pragma unroll
    for (int i = 0; i < 8; ++i) {
      int e8 = i*256 + tid;                // 2048 chunks of 8 = 256x64
      int n = e8 >> 3, k8 = (e8 & 7) << 3;
      *(int4*)(&Bs[n*64 + k8]) = *(const int4*)(WqT + (size_t)n*256 + k0 + k8);
    }
    __syncthreads();
#pragma unroll
    for (int ks = 0; ks < 64; ks += 32) {
      int ko = ks + ((lane >> 4) << 3);
      bf16x8 a[4], b[4];
#pragma unroll
      for (int mi = 0; mi < 4; ++mi) a[mi] = *(const bf16x8*)(&As[(mi*16 + cl)*64 + ko]);
#pragma unroll
      for (int ni = 0; ni < 4; ++ni) b[ni] = *(const bf16x8*)(&Bs[(wid*64 + ni*16 + cl)*64 + ko]);
#pragma unroll
      for (int mi = 0; mi < 4; ++mi)
#pragma unroll
        for (int ni = 0; ni < 4; ++ni)
          acc[mi][ni] = __builtin_amdgcn_mfma_f32_16x16x32_bf16(a[mi], b[ni], acc[mi][ni], 0, 0, 0);
    }
    __syncthreads();
  }
  // ---- softmax over d (32-col groups; group = cols wid*64+32g .. +32) ----
#pragma unroll
  for (int mi = 0; mi < 4; ++mi) {
#pragma unroll
    for (int g = 0; g < 2; ++g) {
#pragma unroll
      for (int r = 0; r < 4; ++r) {
        float e0 = __expf(acc[mi][2*g][r]);
        float e1 = __expf(acc[mi][2*g+1][r]);
        float s = e0 + e1;
        s += __shfl_xor(s, 1); s += __shfl_xor(s, 2);
        s += __shfl_xor(s, 4); s += __shfl_xor(s, 8);
        float inv = 1.0f / s;
        int row = mi*16 + rq + r;
        Qs[row*256 + wid*64 + g*32 + cl]      = f2bf(e0 * inv);
        Qs[row*256 + wid*64 + g*32 + 16 + cl] = f2bf(e1 * inv);
      }
    }
  }
  __syncthreads();
  // ---- phase 2: out[64][256] = Qs @ W2t[bf]^T ----
#pragma unroll
  for (int mi = 0; mi < 4; ++mi)
#pragma unroll
    for (int ni = 0; ni < 4; ++ni)
#pragma unroll
      for (int r = 0; r < 4; ++r) acc[mi][ni][r] = 0.f;
  for (int k0 = 0; k0 < 256; k0 += 64) {
#pragma unroll
    for (int i = 0; i < 8; ++i) {
      int e8 = i*256 + tid;
      int n = e8 >> 3, k8 = (e8 & 7) << 3;
      *(int4*)(&Bs[n*64 + k8]) = *(const int4*)(W2t + ((size_t)bfi*256 + n)*256 + k0 + k8);
    }
    __syncthreads();
#pragma unroll
    for (int ks = 0; ks < 64; ks += 32) {
      int kg = k0 + ks + ((lane >> 4) << 3);
      int kl = ks + ((lane >> 4) << 3);
      bf16x8 a[4], b[4];
#pragma unroll
      for (int mi = 0; mi < 4; ++mi) a[mi] = *(const bf16x8*)(&Qs[(mi*16 + cl)*256 + kg]);
#pragma unroll
      for (int ni = 0; ni < 4; ++ni) b[ni] = *(const bf16x8*)(&Bs[(wid*64 + ni*16 + cl)*64 + kl]);
#pragma unroll
      for (int mi = 0; mi < 4; ++mi)
#pragma unroll
        for (int ni = 0; ni < 4; ++ni)
          acc[mi][ni] = __builtin_amdgcn_mfma_f32_16x16x32_bf16(a[mi], b[ni], acc[mi][ni], 0, 0, 0);
    }
    __syncthreads();
  }
#pragma unroll
  for (int mi = 0; mi < 4; ++mi)
#pragma unroll
    for (int ni = 0; ni < 4; ++ni)
#pragma unroll
      for (int r = 0; r < 4; ++r)
        out[(size_t)(rowbase + mi*16 + rq + r)*256 + wid*64 + ni*16 + cl] = acc[mi][ni][r];
}

extern "C" void kernel_launch(void* const* d_in, const int* in_sizes, int n_in,
                              void* d_out, int out_size, void* d_ws, size_t ws_size,
                              hipStream_t stream) {
  const float* x  = (const float*)d_in[0];
  const float* Wq = (const float*)d_in[1];
  const float* Wk = (const float*)d_in[2];
  const float* Wv = (const float*)d_in[3];
  const float* Wo = (const float*)d_in[4];
  float* out = (float*)d_out;

  // ws layout (bf16 elements unless noted), total ~133.4 MiB
  unsigned short* Ek   = (unsigned short*)d_ws;        // 131072*256
  unsigned short* Vb   = Ek   + 33554432;              // 131072*256
  unsigned short* WkvT = Vb   + 33554432;              // 512*256
  unsigned short* WqT  = WkvT + 131072;                // 256*256
  unsigned short* W2t  = WqT  + 65536;                 // 32*256*256
  float*          ctx  = (float*)(W2t + 2097152);      // 32*8*32*33 f32

  hipMemsetAsync(ctx, 0, (size_t)32*8*32*33*4, stream);
  k0_prep  <<<768,  256, 0, stream>>>(Wq, Wk, Wv, WqT, WkvT);
  k1_kvproj<<<4096, 256, 0, stream>>>(x, WkvT, Ek, Vb);
  k2a_ctx  <<<1024, 256, 0, stream>>>(Ek, Vb, ctx);
  k2b_w2   <<<256,  256, 0, stream>>>(ctx, Wo, W2t);
  k3_fused <<<2048, 256, 0, stream>>>(x, WqT, W2t, out);
}

// Round 2
// 312.017 us; speedup vs baseline: 1.0650x; 1.0650x over previous
//
#include <hip/hip_runtime.h>
#include <hip/hip_bf16.h>

// SpatialLinearAttention: b=2,f=16,h=w=64,c=256, heads=8, D=32
// BF=32 fused batch, n=4096, hD=256.
// out[n,c] = sum_hd softmax_d(xWq)[n,hd] * W2[hd,c]
// W2[hd,c] = sum_e (ctx[h,d,e]/den[h,d]) * Wo[h*32+e,c]
// ctx[h,d,e] = sum_n exp(xWk)[n,h*32+d] * (xWv)[n,h*32+e];  den = sum_n exp(xWk)

typedef __attribute__((ext_vector_type(8))) short bf16x8;
typedef __attribute__((ext_vector_type(4))) float f32x4;

__device__ __forceinline__ unsigned short f2bf(float x) {
  union { float f; unsigned u; } c; c.f = x;
  unsigned r = (c.u + 0x7FFFu + ((c.u >> 16) & 1u)) >> 16;  // RNE
  return (unsigned short)r;
}

// async 16B global->LDS. lds ptr must be WAVE-UNIFORM; each lane writes base+lane*16.
__device__ __forceinline__ void gl16(const unsigned short* g, unsigned short* l) {
  __builtin_amdgcn_global_load_lds((const __attribute__((address_space(1))) void*)g,
                                   (__attribute__((address_space(3))) void*)l, 16, 0, 0);
}

// ---------------- K0: transpose & convert weights to [N][K] bf16 ----------------
__global__ __launch_bounds__(256) void k0_prep(const float* __restrict__ Wq,
                                               const float* __restrict__ Wk,
                                               const float* __restrict__ Wv,
                                               unsigned short* __restrict__ WqT,
                                               unsigned short* __restrict__ WkvT) {
  int r = blockIdx.x, c = threadIdx.x;
  if (r < 256)      WqT [(r      )*256 + c] = f2bf(Wq[c*256 + r]);
  else if (r < 512) WkvT[(r - 256)*256 + c] = f2bf(Wk[c*256 + (r-256)]);
  else              WkvT[(r - 256)*256 + c] = f2bf(Wv[c*256 + (r-512)]);
}

// ---------------- K1: kv projection GEMM, epilogue exp() for k ----------------
// C[131072][512] = x(f32,[M][256]) @ WkvT^T ; cols 0..255 -> Ek=exp(.), 256..511 -> V
// LDS tiles XOR-swizzled: 16B slot s of row r stored at physical slot s^(r&7).
__global__ __launch_bounds__(256) void k1_kvproj(const float* __restrict__ x,
                                                 const unsigned short* __restrict__ WkvT,
                                                 unsigned short* __restrict__ Ek,
                                                 unsigned short* __restrict__ Vb) {
  __shared__ unsigned short As[128*64];   // [r][64k] bf16, swizzled
  __shared__ unsigned short Bs[128*64];   // [n][64k] bf16, swizzled
  // XCD-bijective swizzle (grid 4096 = 8*512): 4 N-tiles of one A-strip share an XCD
  int orig = blockIdx.x;
  int bid  = ((orig & 7) << 9) | (orig >> 3);
  int mt = bid >> 2, nt = bid & 3;
  int mbase = mt * 128, nbase = nt * 128;
  int tid = threadIdx.x;
  int lane = tid & 63, wid = tid >> 6;
  int wr = wid >> 1, wc = wid & 1;
  int cl = lane & 15, rq = (lane >> 4) << 2, fs = lane >> 4;
  f32x4 acc[4][4] = {};
  for (int k0 = 0; k0 < 256; k0 += 64) {
    // stage A: 128 rows x 8 slots(16B); reg-convert f32->bf16, swizzled ds_write_b128
#pragma unroll
    for (int i = 0; i < 4; ++i) {
      int ch = i*256 + tid;
      int r = ch >> 3, s = ch & 7;
      const float* src = x + (size_t)(mbase + r)*256 + k0 + s*8;
      float4 v0 = *(const float4*)src;
      float4 v1 = *(const float4*)(src + 4);
      union { ushort4 u4[2]; int4 i4; } pk;
      pk.u4[0].x = f2bf(v0.x); pk.u4[0].y = f2bf(v0.y); pk.u4[0].z = f2bf(v0.z); pk.u4[0].w = f2bf(v0.w);
      pk.u4[1].x = f2bf(v1.x); pk.u4[1].y = f2bf(v1.y); pk.u4[1].z = f2bf(v1.z); pk.u4[1].w = f2bf(v1.w);
      *(int4*)(&As[r*64 + ((s ^ (r & 7)) << 3)]) = pk.i4;
    }
    // stage B: global_load_lds direct, inverse-swizzled per-lane SOURCE, linear LDS dest
#pragma unroll
    for (int i = 0; i < 4; ++i) {
      int ch = i*256 + tid;                // = i*256 + wid*64 + lane
      int r = ch >> 3, s = ch & 7;
      gl16(WkvT + (size_t)(nbase + r)*256 + k0 + ((s ^ (r & 7)) << 3),
           &Bs[(i*256 + wid*64) * 8]);     // wave-uniform dest
    }
    __syncthreads();
#pragma unroll
    for (int ks = 0; ks < 64; ks += 32) {
      int ls = ks >> 3;                    // base slot 0 or 4
      bf16x8 a[4], b[4];
#pragma unroll
      for (int mi = 0; mi < 4; ++mi) {
        int r = wr*64 + mi*16 + cl;
        a[mi] = *(const bf16x8*)(&As[r*64 + (((ls + fs) ^ (r & 7)) << 3)]);
      }
#pragma unroll
      for (int ni = 0; ni < 4; ++ni) {
        int r = wc*64 + ni*16 + cl;
        b[ni] = *(const bf16x8*)(&Bs[r*64 + (((ls + fs) ^ (r & 7)) << 3)]);
      }
#pragma unroll
      for (int mi = 0; mi < 4; ++mi)
#pragma unroll
        for (int ni = 0; ni < 4; ++ni)
          acc[mi][ni] = __builtin_amdgcn_mfma_f32_16x16x32_bf16(a[mi], b[ni], acc[mi][ni], 0, 0, 0);
    }
    __syncthreads();
  }
#pragma unroll
  for (int mi = 0; mi < 4; ++mi)
#pragma unroll
    for (int ni = 0; ni < 4; ++ni) {
      int col = nbase + wc*64 + ni*16 + cl;
#pragma unroll
      for (int r = 0; r < 4; ++r) {
        int row = mbase + wr*64 + mi*16 + rq + r;
        float v = acc[mi][ni][r];
        if (col < 256) Ek[(size_t)row*256 + col]       = f2bf(__expf(v));
        else           Vb[(size_t)row*256 + col - 256] = f2bf(v);
      }
    }
}

// ---------------- K2a: context partials ctx[bf][h][d][e] (+den at e=32) ----------------
__global__ __launch_bounds__(256) void k2a_ctx(const unsigned short* __restrict__ Ek,
                                               const unsigned short* __restrict__ Vb,
                                               float* __restrict__ ctx) {
  __shared__ float ekf[128*32];
  __shared__ float vf [128*32];
  __shared__ float clds[32*33];
  int bid = blockIdx.x;                    // (bf*8 + h)*4 + s
  int s = bid & 3, h = (bid >> 2) & 7, bfi = bid >> 5;
  int tid = threadIdx.x;
  for (int i = tid; i < 32*33; i += 256) clds[i] = 0.f;
  int p = tid & 31, ss = tid >> 5;
  int d0 = (p & 7) << 2;                   // d quad
  int e0 = (p >> 3) << 3;                  // e oct
  float acc[4][8] = {};
  float den[4] = {};
  size_t rowbase = (size_t)bfi*4096 + (size_t)s*1024;
  int nn = tid >> 1, hf = tid & 1;
  for (int ch = 0; ch < 8; ++ch) {
    __syncthreads();                       // protect LDS from previous chunk's readers
    {
      size_t g = (rowbase + ch*128 + nn) * 256 + h*32 + hf*16;
      int4 a0 = *(const int4*)(Ek + g);
      int4 a1 = *(const int4*)(Ek + g + 8);
      int4 b0 = *(const int4*)(Vb + g);
      int4 b1 = *(const int4*)(Vb + g + 8);
      unsigned* pu;
      float t[16];
      pu = (unsigned*)&a0;
#pragma unroll
      for (int i = 0; i < 4; ++i) { union{unsigned u; float f;} lo, hi; lo.u = pu[i] << 16; hi.u = pu[i] & 0xFFFF0000u; t[2*i] = lo.f; t[2*i+1] = hi.f; }
      pu = (unsigned*)&a1;
#pragma unroll
      for (int i = 0; i < 4; ++i) { union{unsigned u; float f;} lo, hi; lo.u = pu[i] << 16; hi.u = pu[i] & 0xFFFF0000u; t[8+2*i] = lo.f; t[8+2*i+1] = hi.f; }
#pragma unroll
      for (int i = 0; i < 4; ++i)
        *(float4*)(&ekf[nn*32 + hf*16 + 4*i]) = make_float4(t[4*i], t[4*i+1], t[4*i+2], t[4*i+3]);
      pu = (unsigned*)&b0;
#pragma unroll
      for (int i = 0; i < 4; ++i) { union{unsigned u; float f;} lo, hi; lo.u = pu[i] << 16; hi.u = pu[i] & 0xFFFF0000u; t[2*i] = lo.f; t[2*i+1] = hi.f; }
      pu = (unsigned*)&b1;
#pragma unroll
      for (int i = 0; i < 4; ++i) { union{unsigned u; float f;} lo, hi; lo.u = pu[i] << 16; hi.u = pu[i] & 0xFFFF0000u; t[8+2*i] = lo.f; t[8+2*i+1] = hi.f; }
#pragma unroll
      for (int i = 0; i < 4; ++i)
        *(float4*)(&vf[nn*32 + hf*16 + 4*i]) = make_float4(t[4*i], t[4*i+1], t[4*i+2], t[4*i+3]);
    }
    __syncthreads();
#pragma unroll 4
    for (int rr = 0; rr < 16; ++rr) {
      int n2 = ss*16 + rr;
      float4 e4 = *(const float4*)(&ekf[n2*32 + d0]);
      float4 v0 = *(const float4*)(&vf [n2*32 + e0]);
      float4 v1 = *(const float4*)(&vf [n2*32 + e0 + 4]);
#pragma unroll
      for (int i = 0; i < 4; ++i) {
        float e = ((float*)&e4)[i];
        acc[i][0] += e * v0.x; acc[i][1] += e * v0.y; acc[i][2] += e * v0.z; acc[i][3] += e * v0.w;
        acc[i][4] += e * v1.x; acc[i][5] += e * v1.y; acc[i][6] += e * v1.z; acc[i][7] += e * v1.w;
        den[i] += e;
      }
    }
  }
#pragma unroll
  for (int i = 0; i < 4; ++i) {
#pragma unroll
    for (int j = 0; j < 8; ++j) atomicAdd(&clds[(d0 + i)*33 + e0 + j], acc[i][j]);
    if (e0 == 0) atomicAdd(&clds[(d0 + i)*33 + 32], den[i]);
  }
  __syncthreads();
  float* g = ctx + ((size_t)bfi*8 + h)*(32*33);
  for (int i = tid; i < 32*33; i += 256) atomicAdd(&g[i], clds[i]);
}

// ---------------- K2b: W2t[bf][c][hd] = sum_e (ctx/den) * Wo ----------------
__global__ __launch_bounds__(256) void k2b_w2(const float* __restrict__ ctx,
                                              const float* __restrict__ Wo,
                                              unsigned short* __restrict__ W2t) {
  __shared__ float clds[32*33];
  int bid = blockIdx.x;                    // bf*8 + h
  int h = bid & 7, bfi = bid >> 3;
  int tid = threadIdx.x;                   // = c
  const float* g = ctx + (size_t)bid*(32*33);
  for (int i = tid; i < 32*33; i += 256) clds[i] = g[i];
  __syncthreads();
  float acc[32] = {};
#pragma unroll 4
  for (int e = 0; e < 32; ++e) {
    float w = Wo[(size_t)(h*32 + e)*256 + tid];
#pragma unroll
    for (int d = 0; d < 32; ++d) acc[d] += clds[d*33 + e] * w;
  }
  unsigned short* o = W2t + ((size_t)bfi*256 + tid)*256 + h*32;
#pragma unroll
  for (int d = 0; d < 32; ++d) o[d] = f2bf(acc[d] / clds[d*33 + 32]);
}

// ---------------- K3: fused q-proj -> softmax_d -> @W2t -> out ----------------
__global__ __launch_bounds__(256) void k3_fused(const float* __restrict__ x,
                                                const unsigned short* __restrict__ WqT,
                                                const unsigned short* __restrict__ W2t,
                                                float* __restrict__ out) {
  __shared__ unsigned short As[64*64];     // x strip bf16, swizzled (8 slots/row)
  __shared__ unsigned short Bs[256*64];    // weight K-panel [n][64k], swizzled
  __shared__ unsigned short Qs[64*256];    // softmaxed q strip [row][256], swizzled (32 slots/row)
  // XCD-bijective swizzle (grid 2048 = 8*256): 64 blocks sharing W2t[bf] stay on one XCD
  int orig = blockIdx.x;
  int bid  = ((orig & 7) << 8) | (orig >> 3);
  int rowbase = bid * 64;
  int bfi = bid >> 6;
  int tid = threadIdx.x;
  int lane = tid & 63, wid = tid >> 6;     // wave owns 64-col strip
  int cl = lane & 15, rq = (lane >> 4) << 2, fs = lane >> 4;
  f32x4 acc[4][4] = {};
  // ---- phase 1: C1[64][256] = x @ WqT^T ----
  for (int k0 = 0; k0 < 256; k0 += 64) {
#pragma unroll
    for (int i = 0; i < 2; ++i) {
      int ch = i*256 + tid;
      int r = ch >> 3, s = ch & 7;
      const float* src = x + (size_t)(rowbase + r)*256 + k0 + s*8;
      float4 v0 = *(const float4*)src;
      float4 v1 = *(const float4*)(src + 4);
      union { ushort4 u4[2]; int4 i4; } pk;
      pk.u4[0].x = f2bf(v0.x); pk.u4[0].y = f2bf(v0.y); pk.u4[0].z = f2bf(v0.z); pk.u4[0].w = f2bf(v0.w);
      pk.u4[1].x = f2bf(v1.x); pk.u4[1].y = f2bf(v1.y); pk.u4[1].z = f2bf(v1.z); pk.u4[1].w = f2bf(v1.w);
      *(int4*)(&As[r*64 + ((s ^ (r & 7)) << 3)]) = pk.i4;
    }
#pragma unroll
    for (int i = 0; i < 8; ++i) {
      int ch = i*256 + tid;
      int r = ch >> 3, s = ch & 7;
      gl16(WqT + (size_t)r*256 + k0 + ((s ^ (r & 7)) << 3),
           &Bs[(i*256 + wid*64) * 8]);
    }
    __syncthreads();
#pragma unroll
    for (int ks = 0; ks < 64; ks += 32) {
      int ls = ks >> 3;
      bf16x8 a[4], b[4];
#pragma unroll
      for (int mi = 0; mi < 4; ++mi) {
        int r = mi*16 + cl;
        a[mi] = *(const bf16x8*)(&As[r*64 + (((ls + fs) ^ (r & 7)) << 3)]);
      }
#pragma unroll
      for (int ni = 0; ni < 4; ++ni) {
        int r = wid*64 + ni*16 + cl;
        b[ni] = *(const bf16x8*)(&Bs[r*64 + (((ls + fs) ^ (r & 7)) << 3)]);
      }
#pragma unroll
      for (int mi = 0; mi < 4; ++mi)
#pragma unroll
        for (int ni = 0; ni < 4; ++ni)
          acc[mi][ni] = __builtin_amdgcn_mfma_f32_16x16x32_bf16(a[mi], b[ni], acc[mi][ni], 0, 0, 0);
    }
    __syncthreads();
  }
  // ---- softmax over d (32-col groups); write Qs swizzled (32 slots/row, XOR low 3 bits) ----
#pragma unroll
  for (int mi = 0; mi < 4; ++mi) {
#pragma unroll
    for (int g = 0; g < 2; ++g) {
#pragma unroll
      for (int r = 0; r < 4; ++r) {
        float e0 = __expf(acc[mi][2*g][r]);
        float e1 = __expf(acc[mi][2*g+1][r]);
        float s = e0 + e1;
        s += __shfl_xor(s, 1); s += __shfl_xor(s, 2);
        s += __shfl_xor(s, 4); s += __shfl_xor(s, 8);
        float inv = 1.0f / s;
        int row = mi*16 + rq + r;
        int c0 = wid*64 + g*32 + cl;
        int c1 = c0 + 16;
        Qs[row*256 + (((c0 >> 3) ^ (row & 7)) << 3) + (c0 & 7)] = f2bf(e0 * inv);
        Qs[row*256 + (((c1 >> 3) ^ (row & 7)) << 3) + (c1 & 7)] = f2bf(e1 * inv);
      }
    }
  }
  __syncthreads();
  // ---- phase 2: out[64][256] = Qs @ W2t[bf]^T ----
#pragma unroll
  for (int mi = 0; mi < 4; ++mi)
#pragma unroll
    for (int ni = 0; ni < 4; ++ni)
#pragma unroll
      for (int r = 0; r < 4; ++r) acc[mi][ni][r] = 0.f;
  for (int k0 = 0; k0 < 256; k0 += 64) {
#pragma unroll
    for (int i = 0; i < 8; ++i) {
      int ch = i*256 + tid;
      int r = ch >> 3, s = ch & 7;
      gl16(W2t + ((size_t)bfi*256 + r)*256 + k0 + ((s ^ (r & 7)) << 3),
           &Bs[(i*256 + wid*64) * 8]);
    }
    __syncthreads();
#pragma unroll
    for (int ks = 0; ks < 64; ks += 32) {
      int ls = ks >> 3;
      bf16x8 a[4], b[4];
#pragma unroll
      for (int mi = 0; mi < 4; ++mi) {
        int r = mi*16 + cl;
        int slot = ((k0 + ks) >> 3) + fs;          // 0..31 within Qs row
        a[mi] = *(const bf16x8*)(&Qs[r*256 + ((slot ^ (r & 7)) << 3)]);
      }
#pragma unroll
      for (int ni = 0; ni < 4; ++ni) {
        int r = wid*64 + ni*16 + cl;
        b[ni] = *(const bf16x8*)(&Bs[r*64 + (((ls + fs) ^ (r & 7)) << 3)]);
      }
#pragma unroll
      for (int mi = 0; mi < 4; ++mi)
#pragma unroll
        for (int ni = 0; ni < 4; ++ni)
          acc[mi][ni] = __builtin_amdgcn_mfma_f32_16x16x32_bf16(a[mi], b[ni], acc[mi][ni], 0, 0, 0);
    }
    __syncthreads();
  }
#pragma unroll
  for (int mi = 0; mi < 4; ++mi)
#pragma unroll
    for (int ni = 0; ni < 4; ++ni)
#pragma unroll
      for (int r = 0; r < 4; ++r)
        out[(size_t)(rowbase + mi*16 + rq + r)*256 + wid*64 + ni*16 + cl] = acc[mi][ni][r];
}

extern "C" void kernel_launch(void* const* d_in, const int* in_sizes, int n_in,
                              void* d_out, int out_size, void* d_ws, size_t ws_size,
                              hipStream_t stream) {
  const float* x  = (const float*)d_in[0];
  const float* Wq = (const float*)d_in[1];
  const float* Wk = (const float*)d_in[2];
  const float* Wv = (const float*)d_in[3];
  const float* Wo = (const float*)d_in[4];
  float* out = (float*)d_out;

  // ws layout (bf16 elements unless noted), total ~133.4 MiB
  unsigned short* Ek   = (unsigned short*)d_ws;        // 131072*256
  unsigned short* Vb   = Ek   + 33554432;              // 131072*256
  unsigned short* WkvT = Vb   + 33554432;              // 512*256
  unsigned short* WqT  = WkvT + 131072;                // 256*256
  unsigned short* W2t  = WqT  + 65536;                 // 32*256*256
  float*          ctx  = (float*)(W2t + 2097152);      // 32*8*32*33 f32

  hipMemsetAsync(ctx, 0, (size_t)32*8*32*33*4, stream);
  k0_prep  <<<768,  256, 0, stream>>>(Wq, Wk, Wv, WqT, WkvT);
  k1_kvproj<<<4096, 256, 0, stream>>>(x, WkvT, Ek, Vb);
  k2a_ctx  <<<1024, 256, 0, stream>>>(Ek, Vb, ctx);
  k2b_w2   <<<256,  256, 0, stream>>>(ctx, Wo, W2t);
  k3_fused <<<2048, 256, 0, stream>>>(x, WqT, W2t, out);
}

// Round 3
// 282.776 us; speedup vs baseline: 1.1752x; 1.1034x over previous
//
#include <hip/hip_runtime.h>
#include <hip/hip_bf16.h>

// SpatialLinearAttention: b=2,f=16,h=w=64,c=256, heads=8, D=32
// BF=32 fused batch, n=4096, hD=256.
// out[n,c] = sum_hd softmax_d(xWq)[n,hd] * W2[hd,c]
// W2[hd,c] = sum_e (ctx[h,d,e]/den[h,d]) * Wo[h*32+e,c]
// ctx[h,d,e] = sum_n exp(xWk)[n,h*32+d] * (xWv)[n,h*32+e];  den = sum_n exp(xWk)
// k1f fuses kv-projection GEMM + ctx reduction (Ek/V never touch HBM).

typedef __attribute__((ext_vector_type(8))) short bf16x8;
typedef __attribute__((ext_vector_type(4))) float f32x4;

__device__ __forceinline__ unsigned short f2bf(float x) {
  union { float f; unsigned u; } c; c.f = x;
  unsigned r = (c.u + 0x7FFFu + ((c.u >> 16) & 1u)) >> 16;  // RNE
  return (unsigned short)r;
}

// async 16B global->LDS. lds ptr must be WAVE-UNIFORM; each lane writes base+lane*16.
__device__ __forceinline__ void gl16(const unsigned short* g, unsigned short* l) {
  __builtin_amdgcn_global_load_lds((const __attribute__((address_space(1))) void*)g,
                                   (__attribute__((address_space(3))) void*)l, 16, 0, 0);
}

// ---------------- K0: transpose & convert weights to [N][K] bf16 ----------------
__global__ __launch_bounds__(256) void k0_prep(const float* __restrict__ Wq,
                                               const float* __restrict__ Wk,
                                               const float* __restrict__ Wv,
                                               unsigned short* __restrict__ WqT,
                                               unsigned short* __restrict__ WkvT) {
  int r = blockIdx.x, c = threadIdx.x;
  if (r < 256)      WqT [(r      )*256 + c] = f2bf(Wq[c*256 + r]);
  else if (r < 512) WkvT[(r - 256)*256 + c] = f2bf(Wk[c*256 + (r-256)]);
  else              WkvT[(r - 256)*256 + c] = f2bf(Wv[c*256 + (r-512)]);
}

// ---------------- K1f: fused kv-proj GEMM + exp + ctx reduction ----------------
// Block: 64 rows x 512 cols (cols 0..255 = Ek-logits, 256..511 = V). 512 thr, 8 waves.
// Wave wid owns cols [64*wid, 64*wid+64). BK=32, double-buffered, 1-deep prefetch.
// Epilogue: write C^T slab [c][n] bf16 into retired Bs, then per-head MFMA Ek^T*V -> ctx atomics.
__global__ __launch_bounds__(512, 4) void k1f(const float* __restrict__ x,
                                              const unsigned short* __restrict__ WkvT,
                                              float* __restrict__ ctx) {
  __shared__ unsigned short As[2][64*32];   // 4 KB each, swizzled (4 slots/row)
  __shared__ unsigned short Bs[2][512*32];  // 32 KB each, swizzled
  int bid = blockIdx.x;
  int rowbase = bid * 64;
  int bfi = bid >> 6;
  int tid = threadIdx.x;
  int lane = tid & 63, wid = tid >> 6;
  int cl = lane & 15, rq = (lane >> 4) << 2, fs = lane >> 4;
  f32x4 acc[4][4] = {};

  // A-stage mapping (tid<256): row ar (0..63), 16B slot as_ (0..3)
  int ar = tid >> 2, as_ = tid & 3;
  const float* aptr = x + (size_t)(rowbase + ar)*256 + as_*8;
  int aoff = ar*32 + ((as_ ^ ((ar >> 1) & 3)) << 3);  // swizzled ushort offset in As

  float4 pa0, pa1;
  // ---- prologue: stage k-step 0 ----
  if (tid < 256) { pa0 = *(const float4*)aptr; pa1 = *(const float4*)(aptr + 4); }
#pragma unroll
  for (int i = 0; i < 4; ++i) {
    int ch = i*512 + tid; int r = ch >> 2, s = ch & 3;
    gl16(WkvT + (size_t)r*256 + ((s ^ ((r >> 1) & 3)) << 3), &Bs[0][(i*512 + wid*64)*8]);
  }
  if (tid < 256) {
    union { ushort4 u4[2]; int4 i4; } pk;
    pk.u4[0].x = f2bf(pa0.x); pk.u4[0].y = f2bf(pa0.y); pk.u4[0].z = f2bf(pa0.z); pk.u4[0].w = f2bf(pa0.w);
    pk.u4[1].x = f2bf(pa1.x); pk.u4[1].y = f2bf(pa1.y); pk.u4[1].z = f2bf(pa1.z); pk.u4[1].w = f2bf(pa1.w);
    *(int4*)(&As[0][aoff]) = pk.i4;
  }
  __syncthreads();

  // ---- 2-phase K-loop: 8 steps of BK=32 ----
#pragma unroll
  for (int t = 0; t < 8; ++t) {
    int cur = t & 1, nxt = cur ^ 1;
    if (t < 7) {
      if (tid < 256) { pa0 = *(const float4*)(aptr + (t+1)*32); pa1 = *(const float4*)(aptr + (t+1)*32 + 4); }
#pragma unroll
      for (int i = 0; i < 4; ++i) {
        int ch = i*512 + tid; int r = ch >> 2, s = ch & 3;
        gl16(WkvT + (size_t)r*256 + (t+1)*32 + ((s ^ ((r >> 1) & 3)) << 3), &Bs[nxt][(i*512 + wid*64)*8]);
      }
    }
    bf16x8 a[4], b[4];
#pragma unroll
    for (int mi = 0; mi < 4; ++mi) {
      int r = mi*16 + cl;
      a[mi] = *(const bf16x8*)(&As[cur][r*32 + ((fs ^ ((r >> 1) & 3)) << 3)]);
    }
#pragma unroll
    for (int ni = 0; ni < 4; ++ni) {
      int r = wid*64 + ni*16 + cl;
      b[ni] = *(const bf16x8*)(&Bs[cur][r*32 + ((fs ^ ((r >> 1) & 3)) << 3)]);
    }
#pragma unroll
    for (int mi = 0; mi < 4; ++mi)
#pragma unroll
      for (int ni = 0; ni < 4; ++ni)
        acc[mi][ni] = __builtin_amdgcn_mfma_f32_16x16x32_bf16(a[mi], b[ni], acc[mi][ni], 0, 0, 0);
    if (t < 7 && tid < 256) {
      union { ushort4 u4[2]; int4 i4; } pk;
      pk.u4[0].x = f2bf(pa0.x); pk.u4[0].y = f2bf(pa0.y); pk.u4[0].z = f2bf(pa0.z); pk.u4[0].w = f2bf(pa0.w);
      pk.u4[1].x = f2bf(pa1.x); pk.u4[1].y = f2bf(pa1.y); pk.u4[1].z = f2bf(pa1.z); pk.u4[1].w = f2bf(pa1.w);
      *(int4*)(&As[nxt][aoff]) = pk.i4;
    }
    __syncthreads();
  }

  // ---- epilogue: write transposed slab [c][n] bf16 (swizzled), cols<256 get exp ----
  unsigned short* slabT = &Bs[0][0];       // 512 rows x 64 n (128B rows), overlays both Bs buffers
#pragma unroll
  for (int mi = 0; mi < 4; ++mi)
#pragma unroll
    for (int ni = 0; ni < 4; ++ni) {
      int c = wid*64 + ni*16 + cl;
      int n4 = mi*16 + rq;
      ushort4 w;
      if (wid < 4) {
        w.x = f2bf(__expf(acc[mi][ni][0])); w.y = f2bf(__expf(acc[mi][ni][1]));
        w.z = f2bf(__expf(acc[mi][ni][2])); w.w = f2bf(__expf(acc[mi][ni][3]));
      } else {
        w.x = f2bf(acc[mi][ni][0]); w.y = f2bf(acc[mi][ni][1]);
        w.z = f2bf(acc[mi][ni][2]); w.w = f2bf(acc[mi][ni][3]);
      }
      *(ushort4*)(&slabT[c*64 + (((n4 >> 3) ^ (c & 7)) << 3) + (n4 & 7)]) = w;
    }
  __syncthreads();

  // ---- ctx reduction via MFMA: wave wid handles head wid ----
  // ctx_h[d][e] = sum_n Ek[n, h*32+d] * V[n, h*32+e];  A = Ek^T [d][n], B = V [n][e]
  f32x4 c2[2][2] = {};
  f32x4 c3[2] = {};                        // den via ones-operand MFMA
  bf16x8 bone;
#pragma unroll
  for (int j = 0; j < 8; ++j) bone[j] = (short)0x3F80;  // bf16 1.0
#pragma unroll
  for (int kk = 0; kk < 2; ++kk) {
    bf16x8 af[2], bv[2];
#pragma unroll
    for (int di = 0; di < 2; ++di) {
      int c = wid*32 + di*16 + cl;
      af[di] = *(const bf16x8*)(&slabT[c*64 + (((kk*4 + fs) ^ (c & 7)) << 3)]);
    }
#pragma unroll
    for (int ei = 0; ei < 2; ++ei) {
      int c = 256 + wid*32 + ei*16 + cl;
      bv[ei] = *(const bf16x8*)(&slabT[c*64 + (((kk*4 + fs) ^ (c & 7)) << 3)]);
    }
#pragma unroll
    for (int di = 0; di < 2; ++di) {
#pragma unroll
      for (int ei = 0; ei < 2; ++ei)
        c2[di][ei] = __builtin_amdgcn_mfma_f32_16x16x32_bf16(af[di], bv[ei], c2[di][ei], 0, 0, 0);
      c3[di] = __builtin_amdgcn_mfma_f32_16x16x32_bf16(af[di], bone, c3[di], 0, 0, 0);
    }
  }
  float* cg = ctx + ((size_t)bfi*8 + wid)*(32*33);
#pragma unroll
  for (int di = 0; di < 2; ++di)
#pragma unroll
    for (int ei = 0; ei < 2; ++ei)
#pragma unroll
      for (int r = 0; r < 4; ++r)
        atomicAdd(&cg[(di*16 + rq + r)*33 + ei*16 + cl], c2[di][ei][r]);
  if (cl == 0)
#pragma unroll
    for (int di = 0; di < 2; ++di)
#pragma unroll
      for (int r = 0; r < 4; ++r)
        atomicAdd(&cg[(di*16 + rq + r)*33 + 32], c3[di][r]);
}

// ---------------- K2b: W2t[bf][c][hd] = sum_e (ctx/den) * Wo ----------------
__global__ __launch_bounds__(256) void k2b_w2(const float* __restrict__ ctx,
                                              const float* __restrict__ Wo,
                                              unsigned short* __restrict__ W2t) {
  __shared__ float clds[32*33];
  int bid = blockIdx.x;                    // bf*8 + h
  int h = bid & 7, bfi = bid >> 3;
  int tid = threadIdx.x;                   // = c
  const float* g = ctx + (size_t)bid*(32*33);
  for (int i = tid; i < 32*33; i += 256) clds[i] = g[i];
  __syncthreads();
  float acc[32] = {};
#pragma unroll 4
  for (int e = 0; e < 32; ++e) {
    float w = Wo[(size_t)(h*32 + e)*256 + tid];
#pragma unroll
    for (int d = 0; d < 32; ++d) acc[d] += clds[d*33 + e] * w;
  }
  unsigned short* o = W2t + ((size_t)bfi*256 + tid)*256 + h*32;
#pragma unroll
  for (int d = 0; d < 32; ++d) o[d] = f2bf(acc[d] / clds[d*33 + 32]);
}

// ---------------- K3: fused q-proj -> softmax_d -> @W2t -> out ----------------
__global__ __launch_bounds__(256) void k3_fused(const float* __restrict__ x,
                                                const unsigned short* __restrict__ WqT,
                                                const unsigned short* __restrict__ W2t,
                                                float* __restrict__ out) {
  __shared__ unsigned short As[64*64];     // x strip bf16, swizzled (8 slots/row)
  __shared__ unsigned short Bs[256*64];    // weight K-panel [n][64k], swizzled
  __shared__ unsigned short Qs[64*256];    // softmaxed q strip [row][256], swizzled (32 slots/row)
  // XCD-bijective swizzle (grid 2048 = 8*256): 64 blocks sharing W2t[bf] stay on one XCD
  int orig = blockIdx.x;
  int bid  = ((orig & 7) << 8) | (orig >> 3);
  int rowbase = bid * 64;
  int bfi = bid >> 6;
  int tid = threadIdx.x;
  int lane = tid & 63, wid = tid >> 6;     // wave owns 64-col strip
  int cl = lane & 15, rq = (lane >> 4) << 2, fs = lane >> 4;
  f32x4 acc[4][4] = {};
  // ---- phase 1: C1[64][256] = x @ WqT^T ----
  for (int k0 = 0; k0 < 256; k0 += 64) {
#pragma unroll
    for (int i = 0; i < 2; ++i) {
      int ch = i*256 + tid;
      int r = ch >> 3, s = ch & 7;
      const float* src = x + (size_t)(rowbase + r)*256 + k0 + s*8;
      float4 v0 = *(const float4*)src;
      float4 v1 = *(const float4*)(src + 4);
      union { ushort4 u4[2]; int4 i4; } pk;
      pk.u4[0].x = f2bf(v0.x); pk.u4[0].y = f2bf(v0.y); pk.u4[0].z = f2bf(v0.z); pk.u4[0].w = f2bf(v0.w);
      pk.u4[1].x = f2bf(v1.x); pk.u4[1].y = f2bf(v1.y); pk.u4[1].z = f2bf(v1.z); pk.u4[1].w = f2bf(v1.w);
      *(int4*)(&As[r*64 + ((s ^ (r & 7)) << 3)]) = pk.i4;
    }
#pragma unroll
    for (int i = 0; i < 8; ++i) {
      int ch = i*256 + tid;
      int r = ch >> 3, s = ch & 7;
      gl16(WqT + (size_t)r*256 + k0 + ((s ^ (r & 7)) << 3),
           &Bs[(i*256 + wid*64) * 8]);
    }
    __syncthreads();
#pragma unroll
    for (int ks = 0; ks < 64; ks += 32) {
      int ls = ks >> 3;
      bf16x8 a[4], b[4];
#pragma unroll
      for (int mi = 0; mi < 4; ++mi) {
        int r = mi*16 + cl;
        a[mi] = *(const bf16x8*)(&As[r*64 + (((ls + fs) ^ (r & 7)) << 3)]);
      }
#pragma unroll
      for (int ni = 0; ni < 4; ++ni) {
        int r = wid*64 + ni*16 + cl;
        b[ni] = *(const bf16x8*)(&Bs[r*64 + (((ls + fs) ^ (r & 7)) << 3)]);
      }
#pragma unroll
      for (int mi = 0; mi < 4; ++mi)
#pragma unroll
        for (int ni = 0; ni < 4; ++ni)
          acc[mi][ni] = __builtin_amdgcn_mfma_f32_16x16x32_bf16(a[mi], b[ni], acc[mi][ni], 0, 0, 0);
    }
    __syncthreads();
  }
  // ---- softmax over d (32-col groups); write Qs swizzled (32 slots/row, XOR low 3 bits) ----
#pragma unroll
  for (int mi = 0; mi < 4; ++mi) {
#pragma unroll
    for (int g = 0; g < 2; ++g) {
#pragma unroll
      for (int r = 0; r < 4; ++r) {
        float e0 = __expf(acc[mi][2*g][r]);
        float e1 = __expf(acc[mi][2*g+1][r]);
        float s = e0 + e1;
        s += __shfl_xor(s, 1); s += __shfl_xor(s, 2);
        s += __shfl_xor(s, 4); s += __shfl_xor(s, 8);
        float inv = 1.0f / s;
        int row = mi*16 + rq + r;
        int c0 = wid*64 + g*32 + cl;
        int c1 = c0 + 16;
        Qs[row*256 + (((c0 >> 3) ^ (row & 7)) << 3) + (c0 & 7)] = f2bf(e0 * inv);
        Qs[row*256 + (((c1 >> 3) ^ (row & 7)) << 3) + (c1 & 7)] = f2bf(e1 * inv);
      }
    }
  }
  __syncthreads();
  // ---- phase 2: out[64][256] = Qs @ W2t[bf]^T ----
#pragma unroll
  for (int mi = 0; mi < 4; ++mi)
#pragma unroll
    for (int ni = 0; ni < 4; ++ni)
#pragma unroll
      for (int r = 0; r < 4; ++r) acc[mi][ni][r] = 0.f;
  for (int k0 = 0; k0 < 256; k0 += 64) {
#pragma unroll
    for (int i = 0; i < 8; ++i) {
      int ch = i*256 + tid;
      int r = ch >> 3, s = ch & 7;
      gl16(W2t + ((size_t)bfi*256 + r)*256 + k0 + ((s ^ (r & 7)) << 3),
           &Bs[(i*256 + wid*64) * 8]);
    }
    __syncthreads();
#pragma unroll
    for (int ks = 0; ks < 64; ks += 32) {
      int ls = ks >> 3;
      bf16x8 a[4], b[4];
#pragma unroll
      for (int mi = 0; mi < 4; ++mi) {
        int r = mi*16 + cl;
        int slot = ((k0 + ks) >> 3) + fs;          // 0..31 within Qs row
        a[mi] = *(const bf16x8*)(&Qs[r*256 + ((slot ^ (r & 7)) << 3)]);
      }
#pragma unroll
      for (int ni = 0; ni < 4; ++ni) {
        int r = wid*64 + ni*16 + cl;
        b[ni] = *(const bf16x8*)(&Bs[r*64 + (((ls + fs) ^ (r & 7)) << 3)]);
      }
#pragma unroll
      for (int mi = 0; mi < 4; ++mi)
#pragma unroll
        for (int ni = 0; ni < 4; ++ni)
          acc[mi][ni] = __builtin_amdgcn_mfma_f32_16x16x32_bf16(a[mi], b[ni], acc[mi][ni], 0, 0, 0);
    }
    __syncthreads();
  }
#pragma unroll
  for (int mi = 0; mi < 4; ++mi)
#pragma unroll
    for (int ni = 0; ni < 4; ++ni)
#pragma unroll
      for (int r = 0; r < 4; ++r)
        out[(size_t)(rowbase + mi*16 + rq + r)*256 + wid*64 + ni*16 + cl] = acc[mi][ni][r];
}

extern "C" void kernel_launch(void* const* d_in, const int* in_sizes, int n_in,
                              void* d_out, int out_size, void* d_ws, size_t ws_size,
                              hipStream_t stream) {
  const float* x  = (const float*)d_in[0];
  const float* Wq = (const float*)d_in[1];
  const float* Wk = (const float*)d_in[2];
  const float* Wv = (const float*)d_in[3];
  const float* Wo = (const float*)d_in[4];
  float* out = (float*)d_out;

  // ws layout: WkvT (131072 ush) | WqT (65536 ush) | W2t (2097152 ush) | ctx (270336 f32)
  unsigned short* WkvT = (unsigned short*)d_ws;
  unsigned short* WqT  = WkvT + 131072;
  unsigned short* W2t  = WqT  + 65536;
  float*          ctx  = (float*)(W2t + 2097152);

  hipMemsetAsync(ctx, 0, (size_t)32*8*32*33*4, stream);
  k0_prep <<<768,  256, 0, stream>>>(Wq, Wk, Wv, WqT, WkvT);
  k1f     <<<2048, 512, 0, stream>>>(x, WkvT, ctx);
  k2b_w2  <<<256,  256, 0, stream>>>(ctx, Wo, W2t);
  k3_fused<<<2048, 256, 0, stream>>>(x, WqT, W2t, out);
}

// Round 4
// 172.022 us; speedup vs baseline: 1.9318x; 1.6438x over previous
//
#include <hip/hip_runtime.h>
#include <hip/hip_bf16.h>

// SpatialLinearAttention: b=2,f=16,h=w=64,c=256, heads=8, D=32
// BF=32 fused batch, n=4096, hD=256.
// out[n,c] = sum_hd softmax_d(xWq)[n,hd] * W2[hd,c]
// W2[hd,c] = sum_e (ctx[h,d,e]/den[h,d]) * Wo[h*32+e,c]
// ctx[h,d,e] = sum_n exp(xWk)[n,h*32+d] * (xWv)[n,h*32+e];  den = sum_n exp(xWk)
// k1p: persistent-ish fused kv-proj + ctx reduction. B-in-registers, tall M-chunk,
// non-atomic per-block ctx partials (atomic storm of r3 removed).

typedef __attribute__((ext_vector_type(8))) short bf16x8;
typedef __attribute__((ext_vector_type(4))) float f32x4;

__device__ __forceinline__ unsigned short f2bf(float x) {
  union { float f; unsigned u; } c; c.f = x;
  unsigned r = (c.u + 0x7FFFu + ((c.u >> 16) & 1u)) >> 16;  // RNE
  return (unsigned short)r;
}

// async 16B global->LDS. lds ptr must be WAVE-UNIFORM; each lane writes base+lane*16.
__device__ __forceinline__ void gl16(const unsigned short* g, unsigned short* l) {
  __builtin_amdgcn_global_load_lds((const __attribute__((address_space(1))) void*)g,
                                   (__attribute__((address_space(3))) void*)l, 16, 0, 0);
}

// ---------------- K0: transpose & convert weights to [N][K] bf16 ----------------
__global__ __launch_bounds__(256) void k0_prep(const float* __restrict__ Wq,
                                               const float* __restrict__ Wk,
                                               const float* __restrict__ Wv,
                                               unsigned short* __restrict__ WqT,
                                               unsigned short* __restrict__ WkvT) {
  int r = blockIdx.x, c = threadIdx.x;
  if (r < 256)      WqT [(r      )*256 + c] = f2bf(Wq[c*256 + r]);
  else if (r < 512) WkvT[(r - 256)*256 + c] = f2bf(Wk[c*256 + (r-256)]);
  else              WkvT[(r - 256)*256 + c] = f2bf(Wv[c*256 + (r-512)]);
}

// ---------------- K1p: fused kv-proj GEMM + exp + ctx reduction ----------------
// Grid 512 x 512thr. Block: 256 rows x 512 cols, K=256 fully in-register for B.
// Wave wid owns cols [64*wid, 64*wid+64): waves 0-3 = Ek logits, 4-7 = V.
// Strip loop: 8 strips of 32 rows. Per strip: stage A->LDS, 64 MFMA (B from regs),
// transpose C to slab (exp on Ek half), 6 ctx-MFMAs accumulate in regs.
// End: non-atomic partial store ctxp[bid][head][32*33].
__global__ __launch_bounds__(512, 2) void k1p(const float* __restrict__ x,
                                              const unsigned short* __restrict__ WkvT,
                                              float* __restrict__ ctxp) {
  __shared__ unsigned short As[2][32*256];   // 16 KB each, swizzled (32 slots/row)
  __shared__ unsigned short slab[512*32];    // 32 KB: C^T [c][32n], swizzled (4 slots/row)
  int bid = blockIdx.x;
  size_t rowbase = (size_t)bid * 256;
  int tid = threadIdx.x;
  int lane = tid & 63, wid = tid >> 6;
  int cl = lane & 15, rq = (lane >> 4) << 2, fs = lane >> 4;

  // ---- B fragments in registers (128 VGPR): one-time, L2/L3-hot ----
  bf16x8 bfr[4][8];
#pragma unroll
  for (int nf = 0; nf < 4; ++nf)
#pragma unroll
    for (int kk = 0; kk < 8; ++kk)
      bfr[nf][kk] = *(const bf16x8*)(WkvT + (size_t)(wid*64 + nf*16 + cl)*256 + kk*32 + fs*8);

  // ---- ctx accumulators (head = wid), live across strips ----
  f32x4 c2a = {}, c2b = {}, c2c = {}, c2d = {};  // [di][ei] = {a,b;c,d}
  f32x4 c3a = {}, c3b = {};                      // den, di=0/1
  bf16x8 bone;
#pragma unroll
  for (int j = 0; j < 8; ++j) bone[j] = (short)0x3F80;  // bf16 1.0

  // ---- A staging map: 2 chunks of 8 floats per thread ----
  int ar = tid >> 5, as_ = tid & 31;             // row (0..15), slot (0..31)
  int aw0 = ar*256 + ((as_ ^ (ar & 7)) << 3);    // chunk0 -> row ar
  int aw1 = (16 + ar)*256 + ((as_ ^ (ar & 7)) << 3);  // chunk1 -> row 16+ar
  const float* ap = x + (rowbase + ar)*256 + as_*8;

  // prologue: load strip 0
  float4 pa0 = *(const float4*)ap;
  float4 pa1 = *(const float4*)(ap + 4);
  float4 pa2 = *(const float4*)(ap + 16*256);
  float4 pa3 = *(const float4*)(ap + 16*256 + 4);

  for (int t = 0; t < 8; ++t) {
    unsigned short* Ab = &As[t & 1][0];
    // convert staged strip -> LDS
    {
      union { ushort4 u4[2]; int4 i4; } pk;
      pk.u4[0].x = f2bf(pa0.x); pk.u4[0].y = f2bf(pa0.y); pk.u4[0].z = f2bf(pa0.z); pk.u4[0].w = f2bf(pa0.w);
      pk.u4[1].x = f2bf(pa1.x); pk.u4[1].y = f2bf(pa1.y); pk.u4[1].z = f2bf(pa1.z); pk.u4[1].w = f2bf(pa1.w);
      *(int4*)(&Ab[aw0]) = pk.i4;
      pk.u4[0].x = f2bf(pa2.x); pk.u4[0].y = f2bf(pa2.y); pk.u4[0].z = f2bf(pa2.z); pk.u4[0].w = f2bf(pa2.w);
      pk.u4[1].x = f2bf(pa3.x); pk.u4[1].y = f2bf(pa3.y); pk.u4[1].z = f2bf(pa3.z); pk.u4[1].w = f2bf(pa3.w);
      *(int4*)(&Ab[aw1]) = pk.i4;
    }
    __syncthreads();
    // prefetch next strip (consumed at next iteration's convert)
    if (t < 7) {
      const float* apn = ap + (size_t)(t + 1)*32*256;
      pa0 = *(const float4*)apn;
      pa1 = *(const float4*)(apn + 4);
      pa2 = *(const float4*)(apn + 16*256);
      pa3 = *(const float4*)(apn + 16*256 + 4);
    }
    // main MFMA: 32 rows x 64 cols per wave, B from regs
    f32x4 acc0[4] = {};
    f32x4 acc1[4] = {};
#pragma unroll
    for (int kk = 0; kk < 8; ++kk) {
      int so = (((kk*4 + fs) ^ (cl & 7)) << 3);
      bf16x8 a0 = *(const bf16x8*)(&Ab[cl*256 + so]);
      bf16x8 a1 = *(const bf16x8*)(&Ab[(16 + cl)*256 + so]);
#pragma unroll
      for (int ni = 0; ni < 4; ++ni) {
        acc0[ni] = __builtin_amdgcn_mfma_f32_16x16x32_bf16(a0, bfr[ni][kk], acc0[ni], 0, 0, 0);
        acc1[ni] = __builtin_amdgcn_mfma_f32_16x16x32_bf16(a1, bfr[ni][kk], acc1[ni], 0, 0, 0);
      }
    }
    // transpose to slab [c][n32] bf16 (exp on Ek half: wid<4)
#pragma unroll
    for (int ni = 0; ni < 4; ++ni) {
      int c = wid*64 + ni*16 + cl;
      int sw = (c ^ (c >> 2)) & 3;
      ushort4 w0, w1;
      if (wid < 4) {
        w0.x = f2bf(__expf(acc0[ni][0])); w0.y = f2bf(__expf(acc0[ni][1]));
        w0.z = f2bf(__expf(acc0[ni][2])); w0.w = f2bf(__expf(acc0[ni][3]));
        w1.x = f2bf(__expf(acc1[ni][0])); w1.y = f2bf(__expf(acc1[ni][1]));
        w1.z = f2bf(__expf(acc1[ni][2])); w1.w = f2bf(__expf(acc1[ni][3]));
      } else {
        w0.x = f2bf(acc0[ni][0]); w0.y = f2bf(acc0[ni][1]);
        w0.z = f2bf(acc0[ni][2]); w0.w = f2bf(acc0[ni][3]);
        w1.x = f2bf(acc1[ni][0]); w1.y = f2bf(acc1[ni][1]);
        w1.z = f2bf(acc1[ni][2]); w1.w = f2bf(acc1[ni][3]);
      }
      *(ushort4*)(&slab[c*32 + (((rq >> 3) ^ sw) << 3) + (rq & 7)]) = w0;
      *(ushort4*)(&slab[c*32 + ((((16 + rq) >> 3) ^ sw) << 3) + (rq & 7)]) = w1;
    }
    __syncthreads();
    // ctx accumulate: wave wid = head wid. A = Ek^T [d][n], B = V [n][e]
    {
      int ca0 = wid*32 + cl,        ca1 = wid*32 + 16 + cl;
      int cb0 = 256 + wid*32 + cl,  cb1 = 256 + wid*32 + 16 + cl;
      bf16x8 af0 = *(const bf16x8*)(&slab[ca0*32 + ((fs ^ ((ca0 ^ (ca0 >> 2)) & 3)) << 3)]);
      bf16x8 af1 = *(const bf16x8*)(&slab[ca1*32 + ((fs ^ ((ca1 ^ (ca1 >> 2)) & 3)) << 3)]);
      bf16x8 bv0 = *(const bf16x8*)(&slab[cb0*32 + ((fs ^ ((cb0 ^ (cb0 >> 2)) & 3)) << 3)]);
      bf16x8 bv1 = *(const bf16x8*)(&slab[cb1*32 + ((fs ^ ((cb1 ^ (cb1 >> 2)) & 3)) << 3)]);
      c2a = __builtin_amdgcn_mfma_f32_16x16x32_bf16(af0, bv0, c2a, 0, 0, 0);
      c2b = __builtin_amdgcn_mfma_f32_16x16x32_bf16(af0, bv1, c2b, 0, 0, 0);
      c2c = __builtin_amdgcn_mfma_f32_16x16x32_bf16(af1, bv0, c2c, 0, 0, 0);
      c2d = __builtin_amdgcn_mfma_f32_16x16x32_bf16(af1, bv1, c2d, 0, 0, 0);
      c3a = __builtin_amdgcn_mfma_f32_16x16x32_bf16(af0, bone, c3a, 0, 0, 0);
      c3b = __builtin_amdgcn_mfma_f32_16x16x32_bf16(af1, bone, c3b, 0, 0, 0);
    }
  }
  // ---- non-atomic partial store: ctxp[bid][head][d*33 + e], den at e=32 ----
  float* cp = ctxp + ((size_t)bid*8 + wid)*1056;
#pragma unroll
  for (int r = 0; r < 4; ++r) {
    cp[(rq + r)*33 + cl]            = c2a[r];
    cp[(rq + r)*33 + 16 + cl]       = c2b[r];
    cp[(16 + rq + r)*33 + cl]       = c2c[r];
    cp[(16 + rq + r)*33 + 16 + cl]  = c2d[r];
  }
  if (cl == 0) {
#pragma unroll
    for (int r = 0; r < 4; ++r) {
      cp[(rq + r)*33 + 32]      = c3a[r];
      cp[(16 + rq + r)*33 + 32] = c3b[r];
    }
  }
}

// ---------------- K2b: W2t[bf][c][hd] = sum_e (ctx/den) * Wo ----------------
__global__ __launch_bounds__(256) void k2b_w2(const float* __restrict__ ctxp,
                                              const float* __restrict__ Wo,
                                              unsigned short* __restrict__ W2t) {
  __shared__ float clds[32*33];
  int bid = blockIdx.x;                    // bf*8 + h
  int h = bid & 7, bfi = bid >> 3;
  int tid = threadIdx.x;                   // = c
  for (int i = tid; i < 1056; i += 256) {
    float s = 0.f;
#pragma unroll
    for (int p = 0; p < 16; ++p)
      s += ctxp[((size_t)(bfi*16 + p)*8 + h)*1056 + i];
    clds[i] = s;
  }
  __syncthreads();
  float acc[32] = {};
#pragma unroll 4
  for (int e = 0; e < 32; ++e) {
    float w = Wo[(size_t)(h*32 + e)*256 + tid];
#pragma unroll
    for (int d = 0; d < 32; ++d) acc[d] += clds[d*33 + e] * w;
  }
  unsigned short* o = W2t + ((size_t)bfi*256 + tid)*256 + h*32;
#pragma unroll
  for (int d = 0; d < 32; ++d) o[d] = f2bf(acc[d] / clds[d*33 + 32]);
}

// ---------------- K3: fused q-proj -> softmax_d -> @W2t -> out ----------------
__global__ __launch_bounds__(256) void k3_fused(const float* __restrict__ x,
                                                const unsigned short* __restrict__ WqT,
                                                const unsigned short* __restrict__ W2t,
                                                float* __restrict__ out) {
  __shared__ unsigned short As[64*64];     // x strip bf16, swizzled (8 slots/row)
  __shared__ unsigned short Bs[256*64];    // weight K-panel [n][64k], swizzled
  __shared__ unsigned short Qs[64*256];    // softmaxed q strip [row][256], swizzled (32 slots/row)
  // XCD-bijective swizzle (grid 2048 = 8*256): 64 blocks sharing W2t[bf] stay on one XCD
  int orig = blockIdx.x;
  int bid  = ((orig & 7) << 8) | (orig >> 3);
  int rowbase = bid * 64;
  int bfi = bid >> 6;
  int tid = threadIdx.x;
  int lane = tid & 63, wid = tid >> 6;     // wave owns 64-col strip
  int cl = lane & 15, rq = (lane >> 4) << 2, fs = lane >> 4;
  f32x4 acc[4][4] = {};
  // ---- phase 1: C1[64][256] = x @ WqT^T ----
  for (int k0 = 0; k0 < 256; k0 += 64) {
#pragma unroll
    for (int i = 0; i < 2; ++i) {
      int ch = i*256 + tid;
      int r = ch >> 3, s = ch & 7;
      const float* src = x + (size_t)(rowbase + r)*256 + k0 + s*8;
      float4 v0 = *(const float4*)src;
      float4 v1 = *(const float4*)(src + 4);
      union { ushort4 u4[2]; int4 i4; } pk;
      pk.u4[0].x = f2bf(v0.x); pk.u4[0].y = f2bf(v0.y); pk.u4[0].z = f2bf(v0.z); pk.u4[0].w = f2bf(v0.w);
      pk.u4[1].x = f2bf(v1.x); pk.u4[1].y = f2bf(v1.y); pk.u4[1].z = f2bf(v1.z); pk.u4[1].w = f2bf(v1.w);
      *(int4*)(&As[r*64 + ((s ^ (r & 7)) << 3)]) = pk.i4;
    }
#pragma unroll
    for (int i = 0; i < 8; ++i) {
      int ch = i*256 + tid;
      int r = ch >> 3, s = ch & 7;
      gl16(WqT + (size_t)r*256 + k0 + ((s ^ (r & 7)) << 3),
           &Bs[(i*256 + wid*64) * 8]);
    }
    __syncthreads();
#pragma unroll
    for (int ks = 0; ks < 64; ks += 32) {
      int ls = ks >> 3;
      bf16x8 a[4], b[4];
#pragma unroll
      for (int mi = 0; mi < 4; ++mi) {
        int r = mi*16 + cl;
        a[mi] = *(const bf16x8*)(&As[r*64 + (((ls + fs) ^ (r & 7)) << 3)]);
      }
#pragma unroll
      for (int ni = 0; ni < 4; ++ni) {
        int r = wid*64 + ni*16 + cl;
        b[ni] = *(const bf16x8*)(&Bs[r*64 + (((ls + fs) ^ (r & 7)) << 3)]);
      }
#pragma unroll
      for (int mi = 0; mi < 4; ++mi)
#pragma unroll
        for (int ni = 0; ni < 4; ++ni)
          acc[mi][ni] = __builtin_amdgcn_mfma_f32_16x16x32_bf16(a[mi], b[ni], acc[mi][ni], 0, 0, 0);
    }
    __syncthreads();
  }
  // ---- softmax over d (32-col groups); write Qs swizzled (32 slots/row, XOR low 3 bits) ----
#pragma unroll
  for (int mi = 0; mi < 4; ++mi) {
#pragma unroll
    for (int g = 0; g < 2; ++g) {
#pragma unroll
      for (int r = 0; r < 4; ++r) {
        float e0 = __expf(acc[mi][2*g][r]);
        float e1 = __expf(acc[mi][2*g+1][r]);
        float s = e0 + e1;
        s += __shfl_xor(s, 1); s += __shfl_xor(s, 2);
        s += __shfl_xor(s, 4); s += __shfl_xor(s, 8);
        float inv = 1.0f / s;
        int row = mi*16 + rq + r;
        int c0 = wid*64 + g*32 + cl;
        int c1 = c0 + 16;
        Qs[row*256 + (((c0 >> 3) ^ (row & 7)) << 3) + (c0 & 7)] = f2bf(e0 * inv);
        Qs[row*256 + (((c1 >> 3) ^ (row & 7)) << 3) + (c1 & 7)] = f2bf(e1 * inv);
      }
    }
  }
  __syncthreads();
  // ---- phase 2: out[64][256] = Qs @ W2t[bf]^T ----
#pragma unroll
  for (int mi = 0; mi < 4; ++mi)
#pragma unroll
    for (int ni = 0; ni < 4; ++ni)
#pragma unroll
      for (int r = 0; r < 4; ++r) acc[mi][ni][r] = 0.f;
  for (int k0 = 0; k0 < 256; k0 += 64) {
#pragma unroll
    for (int i = 0; i < 8; ++i) {
      int ch = i*256 + tid;
      int r = ch >> 3, s = ch & 7;
      gl16(W2t + ((size_t)bfi*256 + r)*256 + k0 + ((s ^ (r & 7)) << 3),
           &Bs[(i*256 + wid*64) * 8]);
    }
    __syncthreads();
#pragma unroll
    for (int ks = 0; ks < 64; ks += 32) {
      int ls = ks >> 3;
      bf16x8 a[4], b[4];
#pragma unroll
      for (int mi = 0; mi < 4; ++mi) {
        int r = mi*16 + cl;
        int slot = ((k0 + ks) >> 3) + fs;          // 0..31 within Qs row
        a[mi] = *(const bf16x8*)(&Qs[r*256 + ((slot ^ (r & 7)) << 3)]);
      }
#pragma unroll
      for (int ni = 0; ni < 4; ++ni) {
        int r = wid*64 + ni*16 + cl;
        b[ni] = *(const bf16x8*)(&Bs[r*64 + (((ls + fs) ^ (r & 7)) << 3)]);
      }
#pragma unroll
      for (int mi = 0; mi < 4; ++mi)
#pragma unroll
        for (int ni = 0; ni < 4; ++ni)
          acc[mi][ni] = __builtin_amdgcn_mfma_f32_16x16x32_bf16(a[mi], b[ni], acc[mi][ni], 0, 0, 0);
    }
    __syncthreads();
  }
#pragma unroll
  for (int mi = 0; mi < 4; ++mi)
#pragma unroll
    for (int ni = 0; ni < 4; ++ni)
#pragma unroll
      for (int r = 0; r < 4; ++r)
        out[(size_t)(rowbase + mi*16 + rq + r)*256 + wid*64 + ni*16 + cl] = acc[mi][ni][r];
}

extern "C" void kernel_launch(void* const* d_in, const int* in_sizes, int n_in,
                              void* d_out, int out_size, void* d_ws, size_t ws_size,
                              hipStream_t stream) {
  const float* x  = (const float*)d_in[0];
  const float* Wq = (const float*)d_in[1];
  const float* Wk = (const float*)d_in[2];
  const float* Wv = (const float*)d_in[3];
  const float* Wo = (const float*)d_in[4];
  float* out = (float*)d_out;

  // ws layout: WkvT (131072 ush) | WqT (65536 ush) | W2t (2097152 ush) | ctxp (512*8*1056 f32)
  unsigned short* WkvT = (unsigned short*)d_ws;
  unsigned short* WqT  = WkvT + 131072;
  unsigned short* W2t  = WqT  + 65536;
  float*          ctxp = (float*)(W2t + 2097152);

  k0_prep <<<768,  256, 0, stream>>>(Wq, Wk, Wv, WqT, WkvT);
  k1p     <<<512,  512, 0, stream>>>(x, WkvT, ctxp);
  k2b_w2  <<<256,  256, 0, stream>>>(ctxp, Wo, W2t);
  k3_fused<<<2048, 256, 0, stream>>>(x, WqT, W2t, out);
}

// Round 5
// 159.181 us; speedup vs baseline: 2.0876x; 1.0807x over previous
//
#include <hip/hip_runtime.h>
#include <hip/hip_bf16.h>

// SpatialLinearAttention: b=2,f=16,h=w=64,c=256, heads=8, D=32
// BF=32 fused batch, n=4096, hD=256.
// out[n,c] = sum_hd softmax_d(xWq)[n,hd] * W2[hd,c]
// W2[hd,c] = sum_e (ctx[h,d,e]/den[h,d]) * Wo[h*32+e,c]
// ctx[h,d,e] = sum_n exp(xWk)[n,h*32+d] * (xWv)[n,h*32+e];  den = sum_n exp(xWk)
// k1p: fused kv-proj + ctx reduction, B-in-registers, per-block partials.
// k3p: fused q-proj + softmax + @W2t, B-in-registers (both panels), 256-row blocks.

typedef __attribute__((ext_vector_type(8))) short bf16x8;
typedef __attribute__((ext_vector_type(4))) float f32x4;

__device__ __forceinline__ unsigned short f2bf(float x) {
  union { float f; unsigned u; } c; c.f = x;
  unsigned r = (c.u + 0x7FFFu + ((c.u >> 16) & 1u)) >> 16;  // RNE
  return (unsigned short)r;
}

// ---------------- K0: transpose & convert weights to [N][K] bf16 ----------------
__global__ __launch_bounds__(256) void k0_prep(const float* __restrict__ Wq,
                                               const float* __restrict__ Wk,
                                               const float* __restrict__ Wv,
                                               unsigned short* __restrict__ WqT,
                                               unsigned short* __restrict__ WkvT) {
  int r = blockIdx.x, c = threadIdx.x;
  if (r < 256)      WqT [(r      )*256 + c] = f2bf(Wq[c*256 + r]);
  else if (r < 512) WkvT[(r - 256)*256 + c] = f2bf(Wk[c*256 + (r-256)]);
  else              WkvT[(r - 256)*256 + c] = f2bf(Wv[c*256 + (r-512)]);
}

// ---------------- K1p: fused kv-proj GEMM + exp + ctx reduction ----------------
__global__ __launch_bounds__(512, 2) void k1p(const float* __restrict__ x,
                                              const unsigned short* __restrict__ WkvT,
                                              float* __restrict__ ctxp) {
  __shared__ unsigned short As[2][32*256];   // 16 KB each, swizzled (32 slots/row)
  __shared__ unsigned short slab[512*32];    // 32 KB: C^T [c][32n], swizzled (4 slots/row)
  int bid = blockIdx.x;
  size_t rowbase = (size_t)bid * 256;
  int tid = threadIdx.x;
  int lane = tid & 63, wid = tid >> 6;
  int cl = lane & 15, rq = (lane >> 4) << 2, fs = lane >> 4;

  // ---- B fragments in registers (128 VGPR): one-time, L2/L3-hot ----
  bf16x8 bfr[4][8];
#pragma unroll
  for (int nf = 0; nf < 4; ++nf)
#pragma unroll
    for (int kk = 0; kk < 8; ++kk)
      bfr[nf][kk] = *(const bf16x8*)(WkvT + (size_t)(wid*64 + nf*16 + cl)*256 + kk*32 + fs*8);

  // ---- ctx accumulators (head = wid), live across strips ----
  f32x4 c2a = {}, c2b = {}, c2c = {}, c2d = {};
  f32x4 c3a = {}, c3b = {};
  bf16x8 bone;
#pragma unroll
  for (int j = 0; j < 8; ++j) bone[j] = (short)0x3F80;  // bf16 1.0

  int ar = tid >> 5, as_ = tid & 31;
  int aw0 = ar*256 + ((as_ ^ (ar & 7)) << 3);
  int aw1 = (16 + ar)*256 + ((as_ ^ (ar & 7)) << 3);
  const float* ap = x + (rowbase + ar)*256 + as_*8;

  float4 pa0 = *(const float4*)ap;
  float4 pa1 = *(const float4*)(ap + 4);
  float4 pa2 = *(const float4*)(ap + 16*256);
  float4 pa3 = *(const float4*)(ap + 16*256 + 4);

  for (int t = 0; t < 8; ++t) {
    unsigned short* Ab = &As[t & 1][0];
    {
      union { ushort4 u4[2]; int4 i4; } pk;
      pk.u4[0].x = f2bf(pa0.x); pk.u4[0].y = f2bf(pa0.y); pk.u4[0].z = f2bf(pa0.z); pk.u4[0].w = f2bf(pa0.w);
      pk.u4[1].x = f2bf(pa1.x); pk.u4[1].y = f2bf(pa1.y); pk.u4[1].z = f2bf(pa1.z); pk.u4[1].w = f2bf(pa1.w);
      *(int4*)(&Ab[aw0]) = pk.i4;
      pk.u4[0].x = f2bf(pa2.x); pk.u4[0].y = f2bf(pa2.y); pk.u4[0].z = f2bf(pa2.z); pk.u4[0].w = f2bf(pa2.w);
      pk.u4[1].x = f2bf(pa3.x); pk.u4[1].y = f2bf(pa3.y); pk.u4[1].z = f2bf(pa3.z); pk.u4[1].w = f2bf(pa3.w);
      *(int4*)(&Ab[aw1]) = pk.i4;
    }
    __syncthreads();
    if (t < 7) {
      const float* apn = ap + (size_t)(t + 1)*32*256;
      pa0 = *(const float4*)apn;
      pa1 = *(const float4*)(apn + 4);
      pa2 = *(const float4*)(apn + 16*256);
      pa3 = *(const float4*)(apn + 16*256 + 4);
    }
    f32x4 acc0[4] = {};
    f32x4 acc1[4] = {};
#pragma unroll
    for (int kk = 0; kk < 8; ++kk) {
      int so = (((kk*4 + fs) ^ (cl & 7)) << 3);
      bf16x8 a0 = *(const bf16x8*)(&Ab[cl*256 + so]);
      bf16x8 a1 = *(const bf16x8*)(&Ab[(16 + cl)*256 + so]);
#pragma unroll
      for (int ni = 0; ni < 4; ++ni) {
        acc0[ni] = __builtin_amdgcn_mfma_f32_16x16x32_bf16(a0, bfr[ni][kk], acc0[ni], 0, 0, 0);
        acc1[ni] = __builtin_amdgcn_mfma_f32_16x16x32_bf16(a1, bfr[ni][kk], acc1[ni], 0, 0, 0);
      }
    }
#pragma unroll
    for (int ni = 0; ni < 4; ++ni) {
      int c = wid*64 + ni*16 + cl;
      int sw = (c ^ (c >> 2)) & 3;
      ushort4 w0, w1;
      if (wid < 4) {
        w0.x = f2bf(__expf(acc0[ni][0])); w0.y = f2bf(__expf(acc0[ni][1]));
        w0.z = f2bf(__expf(acc0[ni][2])); w0.w = f2bf(__expf(acc0[ni][3]));
        w1.x = f2bf(__expf(acc1[ni][0])); w1.y = f2bf(__expf(acc1[ni][1]));
        w1.z = f2bf(__expf(acc1[ni][2])); w1.w = f2bf(__expf(acc1[ni][3]));
      } else {
        w0.x = f2bf(acc0[ni][0]); w0.y = f2bf(acc0[ni][1]);
        w0.z = f2bf(acc0[ni][2]); w0.w = f2bf(acc0[ni][3]);
        w1.x = f2bf(acc1[ni][0]); w1.y = f2bf(acc1[ni][1]);
        w1.z = f2bf(acc1[ni][2]); w1.w = f2bf(acc1[ni][3]);
      }
      *(ushort4*)(&slab[c*32 + (((rq >> 3) ^ sw) << 3) + (rq & 7)]) = w0;
      *(ushort4*)(&slab[c*32 + ((((16 + rq) >> 3) ^ sw) << 3) + (rq & 7)]) = w1;
    }
    __syncthreads();
    {
      int ca0 = wid*32 + cl,        ca1 = wid*32 + 16 + cl;
      int cb0 = 256 + wid*32 + cl,  cb1 = 256 + wid*32 + 16 + cl;
      bf16x8 af0 = *(const bf16x8*)(&slab[ca0*32 + ((fs ^ ((ca0 ^ (ca0 >> 2)) & 3)) << 3)]);
      bf16x8 af1 = *(const bf16x8*)(&slab[ca1*32 + ((fs ^ ((ca1 ^ (ca1 >> 2)) & 3)) << 3)]);
      bf16x8 bv0 = *(const bf16x8*)(&slab[cb0*32 + ((fs ^ ((cb0 ^ (cb0 >> 2)) & 3)) << 3)]);
      bf16x8 bv1 = *(const bf16x8*)(&slab[cb1*32 + ((fs ^ ((cb1 ^ (cb1 >> 2)) & 3)) << 3)]);
      c2a = __builtin_amdgcn_mfma_f32_16x16x32_bf16(af0, bv0, c2a, 0, 0, 0);
      c2b = __builtin_amdgcn_mfma_f32_16x16x32_bf16(af0, bv1, c2b, 0, 0, 0);
      c2c = __builtin_amdgcn_mfma_f32_16x16x32_bf16(af1, bv0, c2c, 0, 0, 0);
      c2d = __builtin_amdgcn_mfma_f32_16x16x32_bf16(af1, bv1, c2d, 0, 0, 0);
      c3a = __builtin_amdgcn_mfma_f32_16x16x32_bf16(af0, bone, c3a, 0, 0, 0);
      c3b = __builtin_amdgcn_mfma_f32_16x16x32_bf16(af1, bone, c3b, 0, 0, 0);
    }
  }
  float* cp = ctxp + ((size_t)bid*8 + wid)*1056;
#pragma unroll
  for (int r = 0; r < 4; ++r) {
    cp[(rq + r)*33 + cl]            = c2a[r];
    cp[(rq + r)*33 + 16 + cl]       = c2b[r];
    cp[(16 + rq + r)*33 + cl]       = c2c[r];
    cp[(16 + rq + r)*33 + 16 + cl]  = c2d[r];
  }
  if (cl == 0) {
#pragma unroll
    for (int r = 0; r < 4; ++r) {
      cp[(rq + r)*33 + 32]      = c3a[r];
      cp[(16 + rq + r)*33 + 32] = c3b[r];
    }
  }
}

// ---------------- K2b: W2t[bf][c][hd] = sum_e (ctx/den) * Wo ----------------
__global__ __launch_bounds__(256) void k2b_w2(const float* __restrict__ ctxp,
                                              const float* __restrict__ Wo,
                                              unsigned short* __restrict__ W2t) {
  __shared__ float clds[32*33];
  int bid = blockIdx.x;                    // bf*8 + h
  int h = bid & 7, bfi = bid >> 3;
  int tid = threadIdx.x;                   // = c
  for (int i = tid; i < 1056; i += 256) {
    float s = 0.f;
#pragma unroll
    for (int p = 0; p < 16; ++p)
      s += ctxp[((size_t)(bfi*16 + p)*8 + h)*1056 + i];
    clds[i] = s;
  }
  __syncthreads();
  float acc[32] = {};
#pragma unroll 4
  for (int e = 0; e < 32; ++e) {
    float w = Wo[(size_t)(h*32 + e)*256 + tid];
#pragma unroll
    for (int d = 0; d < 32; ++d) acc[d] += clds[d*33 + e] * w;
  }
  unsigned short* o = W2t + ((size_t)bfi*256 + tid)*256 + h*32;
#pragma unroll
  for (int d = 0; d < 32; ++d) o[d] = f2bf(acc[d] / clds[d*33 + 32]);
}

// ---------------- K3p: fused q-proj -> softmax_d -> @W2t -> out ----------------
// Grid 512 x 512thr. Block: 256 rows. Wave wid owns output cols [wid*32, wid*32+32)
// == head wid's d-range for phase 1. Both B panels (WqT, W2t[bf]) in registers.
// Strip loop: 8 strips of 32 rows; dbuf As (x) and dbuf Qs; 2 barriers/strip.
__global__ __launch_bounds__(512, 2) void k3p(const float* __restrict__ x,
                                              const unsigned short* __restrict__ WqT,
                                              const unsigned short* __restrict__ W2t,
                                              float* __restrict__ out) {
  __shared__ unsigned short As[2][32*256];   // 16 KB each, swizzled (32 slots/row)
  __shared__ unsigned short Qs[2][32*256];   // 16 KB each, swizzled
  int bid = blockIdx.x;
  size_t rowbase = (size_t)bid * 256;
  int bfi = bid >> 4;                        // 16 blocks per bf
  int tid = threadIdx.x;
  int lane = tid & 63, wid = tid >> 6;
  int cl = lane & 15, rq = (lane >> 4) << 2, fs = lane >> 4;

  // ---- B fragments in registers: bq = WqT (phase1), bw = W2t[bfi] (phase2) ----
  bf16x8 bq[2][8], bw[2][8];
#pragma unroll
  for (int nf = 0; nf < 2; ++nf)
#pragma unroll
    for (int kk = 0; kk < 8; ++kk) {
      bq[nf][kk] = *(const bf16x8*)(WqT + (size_t)(wid*32 + nf*16 + cl)*256 + kk*32 + fs*8);
      bw[nf][kk] = *(const bf16x8*)(W2t + ((size_t)bfi*256 + wid*32 + nf*16 + cl)*256 + kk*32 + fs*8);
    }

  int ar = tid >> 5, as_ = tid & 31;
  int aw0 = ar*256 + ((as_ ^ (ar & 7)) << 3);
  int aw1 = (16 + ar)*256 + ((as_ ^ (ar & 7)) << 3);
  const float* ap = x + (rowbase + ar)*256 + as_*8;

  float4 pa0 = *(const float4*)ap;
  float4 pa1 = *(const float4*)(ap + 4);
  float4 pa2 = *(const float4*)(ap + 16*256);
  float4 pa3 = *(const float4*)(ap + 16*256 + 4);

  for (int t = 0; t < 8; ++t) {
    unsigned short* Ab = &As[t & 1][0];
    unsigned short* Qb = &Qs[t & 1][0];
    // convert staged strip -> LDS
    {
      union { ushort4 u4[2]; int4 i4; } pk;
      pk.u4[0].x = f2bf(pa0.x); pk.u4[0].y = f2bf(pa0.y); pk.u4[0].z = f2bf(pa0.z); pk.u4[0].w = f2bf(pa0.w);
      pk.u4[1].x = f2bf(pa1.x); pk.u4[1].y = f2bf(pa1.y); pk.u4[1].z = f2bf(pa1.z); pk.u4[1].w = f2bf(pa1.w);
      *(int4*)(&Ab[aw0]) = pk.i4;
      pk.u4[0].x = f2bf(pa2.x); pk.u4[0].y = f2bf(pa2.y); pk.u4[0].z = f2bf(pa2.z); pk.u4[0].w = f2bf(pa2.w);
      pk.u4[1].x = f2bf(pa3.x); pk.u4[1].y = f2bf(pa3.y); pk.u4[1].z = f2bf(pa3.z); pk.u4[1].w = f2bf(pa3.w);
      *(int4*)(&Ab[aw1]) = pk.i4;
    }
    __syncthreads();
    if (t < 7) {
      const float* apn = ap + (size_t)(t + 1)*32*256;
      pa0 = *(const float4*)apn;
      pa1 = *(const float4*)(apn + 4);
      pa2 = *(const float4*)(apn + 16*256);
      pa3 = *(const float4*)(apn + 16*256 + 4);
    }
    // ---- phase 1: q logits, B from regs ----
    f32x4 ql[2][2] = {};
#pragma unroll
    for (int kk = 0; kk < 8; ++kk) {
      int so = (((kk*4 + fs) ^ (cl & 7)) << 3);
      bf16x8 a0 = *(const bf16x8*)(&Ab[cl*256 + so]);
      bf16x8 a1 = *(const bf16x8*)(&Ab[(16 + cl)*256 + so]);
#pragma unroll
      for (int nf = 0; nf < 2; ++nf) {
        ql[0][nf] = __builtin_amdgcn_mfma_f32_16x16x32_bf16(a0, bq[nf][kk], ql[0][nf], 0, 0, 0);
        ql[1][nf] = __builtin_amdgcn_mfma_f32_16x16x32_bf16(a1, bq[nf][kk], ql[1][nf], 0, 0, 0);
      }
    }
    // ---- softmax over d (head wid = cols wid*32..+32); write Qs swizzled ----
#pragma unroll
    for (int mf = 0; mf < 2; ++mf) {
#pragma unroll
      for (int r = 0; r < 4; ++r) {
        float e0 = __expf(ql[mf][0][r]);
        float e1 = __expf(ql[mf][1][r]);
        float s = e0 + e1;
        s += __shfl_xor(s, 1); s += __shfl_xor(s, 2);
        s += __shfl_xor(s, 4); s += __shfl_xor(s, 8);
        float inv = 1.0f / s;
        int row = mf*16 + rq + r;
        int c0 = wid*32 + cl;
        int c1 = wid*32 + 16 + cl;
        Qb[row*256 + (((c0 >> 3) ^ (row & 7)) << 3) + (c0 & 7)] = f2bf(e0 * inv);
        Qb[row*256 + (((c1 >> 3) ^ (row & 7)) << 3) + (c1 & 7)] = f2bf(e1 * inv);
      }
    }
    __syncthreads();
    // ---- phase 2: out strip = Qs @ W2t^T, B from regs ----
    f32x4 oa[2][2] = {};
#pragma unroll
    for (int kk = 0; kk < 8; ++kk) {
      int so = (((kk*4 + fs) ^ (cl & 7)) << 3);
      bf16x8 a0 = *(const bf16x8*)(&Qb[cl*256 + so]);
      bf16x8 a1 = *(const bf16x8*)(&Qb[(16 + cl)*256 + so]);
#pragma unroll
      for (int nf = 0; nf < 2; ++nf) {
        oa[0][nf] = __builtin_amdgcn_mfma_f32_16x16x32_bf16(a0, bw[nf][kk], oa[0][nf], 0, 0, 0);
        oa[1][nf] = __builtin_amdgcn_mfma_f32_16x16x32_bf16(a1, bw[nf][kk], oa[1][nf], 0, 0, 0);
      }
    }
    size_t ob = rowbase + (size_t)t*32;
#pragma unroll
    for (int mf = 0; mf < 2; ++mf)
#pragma unroll
      for (int nf = 0; nf < 2; ++nf)
#pragma unroll
        for (int r = 0; r < 4; ++r)
          out[(ob + mf*16 + rq + r)*256 + wid*32 + nf*16 + cl] = oa[mf][nf][r];
  }
}

extern "C" void kernel_launch(void* const* d_in, const int* in_sizes, int n_in,
                              void* d_out, int out_size, void* d_ws, size_t ws_size,
                              hipStream_t stream) {
  const float* x  = (const float*)d_in[0];
  const float* Wq = (const float*)d_in[1];
  const float* Wk = (const float*)d_in[2];
  const float* Wv = (const float*)d_in[3];
  const float* Wo = (const float*)d_in[4];
  float* out = (float*)d_out;

  // ws layout: WkvT (131072 ush) | WqT (65536 ush) | W2t (2097152 ush) | ctxp (512*8*1056 f32)
  unsigned short* WkvT = (unsigned short*)d_ws;
  unsigned short* WqT  = WkvT + 131072;
  unsigned short* W2t  = WqT  + 65536;
  float*          ctxp = (float*)(W2t + 2097152);

  k0_prep <<<768,  256, 0, stream>>>(Wq, Wk, Wv, WqT, WkvT);
  k1p     <<<512,  512, 0, stream>>>(x, WkvT, ctxp);
  k2b_w2  <<<256,  256, 0, stream>>>(ctxp, Wo, W2t);
  k3p     <<<512,  512, 0, stream>>>(x, WqT, W2t, out);
}

// Round 6
// 141.946 us; speedup vs baseline: 2.3411x; 1.1214x over previous
//
#include <hip/hip_runtime.h>
#include <hip/hip_bf16.h>

// SpatialLinearAttention: b=2,f=16,h=w=64,c=256, heads=8, D=32
// BF=32 fused batch, n=4096, hD=256.
// out[n,c] = sum_hd softmax_d(xWq)[n,hd] * W2[hd,c]
// W2[hd,c] = sum_e (ctx[h,d,e]/den[h,d]) * Wo[h*32+e,c]
// ctx[h,d,e] = sum_n exp(xWk)[n,h*32+d] * (xWv)[n,h*32+e];  den = sum_n exp(xWk)
// k1p: fused kv-proj + ctx reduction, B-in-registers, per-block partials.
// k3s: fused q-proj + softmax + @W2t; operand-swapped MFMAs, 1-barrier pipeline.

typedef __attribute__((ext_vector_type(8))) short bf16x8;
typedef __attribute__((ext_vector_type(4))) float f32x4;

__device__ __forceinline__ unsigned short f2bf(float x) {
  __hip_bfloat16 h = __float2bfloat16(x);          // HW v_cvt (RNE), 1 VALU op
  union { __hip_bfloat16 b; unsigned short u; } c; c.b = h; return c.u;
}

// ---------------- K0: transpose & convert weights to [N][K] bf16 ----------------
__global__ __launch_bounds__(256) void k0_prep(const float* __restrict__ Wq,
                                               const float* __restrict__ Wk,
                                               const float* __restrict__ Wv,
                                               unsigned short* __restrict__ WqT,
                                               unsigned short* __restrict__ WkvT) {
  int r = blockIdx.x, c = threadIdx.x;
  if (r < 256)      WqT [(r      )*256 + c] = f2bf(Wq[c*256 + r]);
  else if (r < 512) WkvT[(r - 256)*256 + c] = f2bf(Wk[c*256 + (r-256)]);
  else              WkvT[(r - 256)*256 + c] = f2bf(Wv[c*256 + (r-512)]);
}

// ---------------- K1p: fused kv-proj GEMM + exp + ctx reduction ----------------
__global__ __launch_bounds__(512, 2) void k1p(const float* __restrict__ x,
                                              const unsigned short* __restrict__ WkvT,
                                              float* __restrict__ ctxp) {
  __shared__ unsigned short As[2][32*256];   // 16 KB each, swizzled (32 slots/row)
  __shared__ unsigned short slab[512*32];    // 32 KB: C^T [c][32n], swizzled (4 slots/row)
  int bid = blockIdx.x;
  size_t rowbase = (size_t)bid * 256;
  int tid = threadIdx.x;
  int lane = tid & 63, wid = tid >> 6;
  int cl = lane & 15, rq = (lane >> 4) << 2, fs = lane >> 4;

  // ---- B fragments in registers (128 VGPR): one-time, L2/L3-hot ----
  bf16x8 bfr[4][8];
#pragma unroll
  for (int nf = 0; nf < 4; ++nf)
#pragma unroll
    for (int kk = 0; kk < 8; ++kk)
      bfr[nf][kk] = *(const bf16x8*)(WkvT + (size_t)(wid*64 + nf*16 + cl)*256 + kk*32 + fs*8);

  // ---- ctx accumulators (head = wid), live across strips ----
  f32x4 c2a = {}, c2b = {}, c2c = {}, c2d = {};
  f32x4 c3a = {}, c3b = {};
  bf16x8 bone;
#pragma unroll
  for (int j = 0; j < 8; ++j) bone[j] = (short)0x3F80;  // bf16 1.0

  int ar = tid >> 5, as_ = tid & 31;
  int aw0 = ar*256 + ((as_ ^ (ar & 7)) << 3);
  int aw1 = (16 + ar)*256 + ((as_ ^ (ar & 7)) << 3);
  const float* ap = x + (rowbase + ar)*256 + as_*8;

  float4 pa0 = *(const float4*)ap;
  float4 pa1 = *(const float4*)(ap + 4);
  float4 pa2 = *(const float4*)(ap + 16*256);
  float4 pa3 = *(const float4*)(ap + 16*256 + 4);

  for (int t = 0; t < 8; ++t) {
    unsigned short* Ab = &As[t & 1][0];
    {
      union { ushort4 u4[2]; int4 i4; } pk;
      pk.u4[0].x = f2bf(pa0.x); pk.u4[0].y = f2bf(pa0.y); pk.u4[0].z = f2bf(pa0.z); pk.u4[0].w = f2bf(pa0.w);
      pk.u4[1].x = f2bf(pa1.x); pk.u4[1].y = f2bf(pa1.y); pk.u4[1].z = f2bf(pa1.z); pk.u4[1].w = f2bf(pa1.w);
      *(int4*)(&Ab[aw0]) = pk.i4;
      pk.u4[0].x = f2bf(pa2.x); pk.u4[0].y = f2bf(pa2.y); pk.u4[0].z = f2bf(pa2.z); pk.u4[0].w = f2bf(pa2.w);
      pk.u4[1].x = f2bf(pa3.x); pk.u4[1].y = f2bf(pa3.y); pk.u4[1].z = f2bf(pa3.z); pk.u4[1].w = f2bf(pa3.w);
      *(int4*)(&Ab[aw1]) = pk.i4;
    }
    __syncthreads();
    if (t < 7) {
      const float* apn = ap + (size_t)(t + 1)*32*256;
      pa0 = *(const float4*)apn;
      pa1 = *(const float4*)(apn + 4);
      pa2 = *(const float4*)(apn + 16*256);
      pa3 = *(const float4*)(apn + 16*256 + 4);
    }
    f32x4 acc0[4] = {};
    f32x4 acc1[4] = {};
#pragma unroll
    for (int kk = 0; kk < 8; ++kk) {
      int so = (((kk*4 + fs) ^ (cl & 7)) << 3);
      bf16x8 a0 = *(const bf16x8*)(&Ab[cl*256 + so]);
      bf16x8 a1 = *(const bf16x8*)(&Ab[(16 + cl)*256 + so]);
#pragma unroll
      for (int ni = 0; ni < 4; ++ni) {
        acc0[ni] = __builtin_amdgcn_mfma_f32_16x16x32_bf16(a0, bfr[ni][kk], acc0[ni], 0, 0, 0);
        acc1[ni] = __builtin_amdgcn_mfma_f32_16x16x32_bf16(a1, bfr[ni][kk], acc1[ni], 0, 0, 0);
      }
    }
#pragma unroll
    for (int ni = 0; ni < 4; ++ni) {
      int c = wid*64 + ni*16 + cl;
      int sw = (c ^ (c >> 2)) & 3;
      ushort4 w0, w1;
      if (wid < 4) {
        w0.x = f2bf(__expf(acc0[ni][0])); w0.y = f2bf(__expf(acc0[ni][1]));
        w0.z = f2bf(__expf(acc0[ni][2])); w0.w = f2bf(__expf(acc0[ni][3]));
        w1.x = f2bf(__expf(acc1[ni][0])); w1.y = f2bf(__expf(acc1[ni][1]));
        w1.z = f2bf(__expf(acc1[ni][2])); w1.w = f2bf(__expf(acc1[ni][3]));
      } else {
        w0.x = f2bf(acc0[ni][0]); w0.y = f2bf(acc0[ni][1]);
        w0.z = f2bf(acc0[ni][2]); w0.w = f2bf(acc0[ni][3]);
        w1.x = f2bf(acc1[ni][0]); w1.y = f2bf(acc1[ni][1]);
        w1.z = f2bf(acc1[ni][2]); w1.w = f2bf(acc1[ni][3]);
      }
      *(ushort4*)(&slab[c*32 + (((rq >> 3) ^ sw) << 3) + (rq & 7)]) = w0;
      *(ushort4*)(&slab[c*32 + ((((16 + rq) >> 3) ^ sw) << 3) + (rq & 7)]) = w1;
    }
    __syncthreads();
    {
      int ca0 = wid*32 + cl,        ca1 = wid*32 + 16 + cl;
      int cb0 = 256 + wid*32 + cl,  cb1 = 256 + wid*32 + 16 + cl;
      bf16x8 af0 = *(const bf16x8*)(&slab[ca0*32 + ((fs ^ ((ca0 ^ (ca0 >> 2)) & 3)) << 3)]);
      bf16x8 af1 = *(const bf16x8*)(&slab[ca1*32 + ((fs ^ ((ca1 ^ (ca1 >> 2)) & 3)) << 3)]);
      bf16x8 bv0 = *(const bf16x8*)(&slab[cb0*32 + ((fs ^ ((cb0 ^ (cb0 >> 2)) & 3)) << 3)]);
      bf16x8 bv1 = *(const bf16x8*)(&slab[cb1*32 + ((fs ^ ((cb1 ^ (cb1 >> 2)) & 3)) << 3)]);
      c2a = __builtin_amdgcn_mfma_f32_16x16x32_bf16(af0, bv0, c2a, 0, 0, 0);
      c2b = __builtin_amdgcn_mfma_f32_16x16x32_bf16(af0, bv1, c2b, 0, 0, 0);
      c2c = __builtin_amdgcn_mfma_f32_16x16x32_bf16(af1, bv0, c2c, 0, 0, 0);
      c2d = __builtin_amdgcn_mfma_f32_16x16x32_bf16(af1, bv1, c2d, 0, 0, 0);
      c3a = __builtin_amdgcn_mfma_f32_16x16x32_bf16(af0, bone, c3a, 0, 0, 0);
      c3b = __builtin_amdgcn_mfma_f32_16x16x32_bf16(af1, bone, c3b, 0, 0, 0);
    }
  }
  float* cp = ctxp + ((size_t)bid*8 + wid)*1056;
#pragma unroll
  for (int r = 0; r < 4; ++r) {
    cp[(rq + r)*33 + cl]            = c2a[r];
    cp[(rq + r)*33 + 16 + cl]       = c2b[r];
    cp[(16 + rq + r)*33 + cl]       = c2c[r];
    cp[(16 + rq + r)*33 + 16 + cl]  = c2d[r];
  }
  if (cl == 0) {
#pragma unroll
    for (int r = 0; r < 4; ++r) {
      cp[(rq + r)*33 + 32]      = c3a[r];
      cp[(16 + rq + r)*33 + 32] = c3b[r];
    }
  }
}

// ---------------- K2b: W2t[bf][c][hd] = sum_e (ctx/den) * Wo ----------------
__global__ __launch_bounds__(256) void k2b_w2(const float* __restrict__ ctxp,
                                              const float* __restrict__ Wo,
                                              unsigned short* __restrict__ W2t) {
  __shared__ float clds[32*33];
  int bid = blockIdx.x;                    // bf*8 + h
  int h = bid & 7, bfi = bid >> 3;
  int tid = threadIdx.x;                   // = c
  for (int i = tid; i < 1056; i += 256) {
    float s = 0.f;
#pragma unroll
    for (int p = 0; p < 16; ++p)
      s += ctxp[((size_t)(bfi*16 + p)*8 + h)*1056 + i];
    clds[i] = s;
  }
  __syncthreads();
  float acc[32] = {};
#pragma unroll 4
  for (int e = 0; e < 32; ++e) {
    float w = Wo[(size_t)(h*32 + e)*256 + tid];
#pragma unroll
    for (int d = 0; d < 32; ++d) acc[d] += clds[d*33 + e] * w;
  }
  unsigned short* o = W2t + ((size_t)bfi*256 + tid)*256 + h*32;
#pragma unroll
  for (int d = 0; d < 32; ++d) o[d] = f2bf(acc[d] / clds[d*33 + 32]);
}

// ---------------- K3s: fused q-proj -> softmax_d -> @W2t -> out ----------------
// Grid 512 x 512thr, 256 rows/block, 8 strips of 32 rows.
// P1 swapped: ql = mfma(Wq_frag, x_frag) -> lane holds 4 consecutive d per reg
//   (softmax reduce = in-reg sum + shfl_xor 16,32; Qs store = ds_write_b64 x4).
// P2 swapped: oa = mfma(W2_frag, q_frag) -> float4 out stores.
// 1 barrier/strip: [stage As(t+1) | write Qs(t)] bar [P2(t) + P1(t+1)].
__global__ __launch_bounds__(512, 2) void k3s(const float* __restrict__ x,
                                              const unsigned short* __restrict__ WqT,
                                              const unsigned short* __restrict__ W2t,
                                              float* __restrict__ out) {
  __shared__ unsigned short As[2][32*256];   // 16 KB each, swizzled (32 slots/row)
  __shared__ unsigned short Qs[2][32*256];   // 16 KB each, swizzled
  int bid = blockIdx.x;
  size_t rowbase = (size_t)bid * 256;
  int bfi = bid >> 4;                        // 16 blocks per bf
  int tid = threadIdx.x;
  int lane = tid & 63, wid = tid >> 6;
  int cl = lane & 15, rq = (lane >> 4) << 2, fs = lane >> 4;

  // ---- B panels in registers ----
  bf16x8 bq[2][8], bw[2][8];
#pragma unroll
  for (int nf = 0; nf < 2; ++nf)
#pragma unroll
    for (int kk = 0; kk < 8; ++kk) {
      bq[nf][kk] = *(const bf16x8*)(WqT + (size_t)(wid*32 + nf*16 + cl)*256 + kk*32 + fs*8);
      bw[nf][kk] = *(const bf16x8*)(W2t + ((size_t)bfi*256 + wid*32 + nf*16 + cl)*256 + kk*32 + fs*8);
    }

  int ar = tid >> 5, as_ = tid & 31;
  int aw0 = ar*256 + ((as_ ^ (ar & 7)) << 3);
  int aw1 = (16 + ar)*256 + ((as_ ^ (ar & 7)) << 3);
  const float* ap = x + (rowbase + ar)*256 + as_*8;

  // Qs write addresses (per m, nf): row = m*16+cl, hd = wid*32+nf*16+rq
  int qslotbase = wid*4 + (rq >> 3);         // + nf*2
  ushort4 qpk[2][2];

  // ---- prologue: stage strip 0, prefetch strip 1 ----
  float4 pa0 = *(const float4*)ap;
  float4 pa1 = *(const float4*)(ap + 4);
  float4 pa2 = *(const float4*)(ap + 16*256);
  float4 pa3 = *(const float4*)(ap + 16*256 + 4);
  {
    unsigned short* Ab = &As[0][0];
    union { ushort4 u4[2]; int4 i4; } pk;
    pk.u4[0].x = f2bf(pa0.x); pk.u4[0].y = f2bf(pa0.y); pk.u4[0].z = f2bf(pa0.z); pk.u4[0].w = f2bf(pa0.w);
    pk.u4[1].x = f2bf(pa1.x); pk.u4[1].y = f2bf(pa1.y); pk.u4[1].z = f2bf(pa1.z); pk.u4[1].w = f2bf(pa1.w);
    *(int4*)(&Ab[aw0]) = pk.i4;
    pk.u4[0].x = f2bf(pa2.x); pk.u4[0].y = f2bf(pa2.y); pk.u4[0].z = f2bf(pa2.z); pk.u4[0].w = f2bf(pa2.w);
    pk.u4[1].x = f2bf(pa3.x); pk.u4[1].y = f2bf(pa3.y); pk.u4[1].z = f2bf(pa3.z); pk.u4[1].w = f2bf(pa3.w);
    *(int4*)(&Ab[aw1]) = pk.i4;
  }
  {
    const float* apn = ap + 32*256;
    pa0 = *(const float4*)apn;
    pa1 = *(const float4*)(apn + 4);
    pa2 = *(const float4*)(apn + 16*256);
    pa3 = *(const float4*)(apn + 16*256 + 4);
  }
  __syncthreads();
  // P1(0) + softmax(0)
  {
    unsigned short* Ab = &As[0][0];
    f32x4 ql[2][2] = {};
#pragma unroll
    for (int kk = 0; kk < 8; ++kk) {
      int so = (((kk*4 + fs) ^ (cl & 7)) << 3);
      bf16x8 a0 = *(const bf16x8*)(&Ab[cl*256 + so]);
      bf16x8 a1 = *(const bf16x8*)(&Ab[(16 + cl)*256 + so]);
#pragma unroll
      for (int nf = 0; nf < 2; ++nf) {
        ql[0][nf] = __builtin_amdgcn_mfma_f32_16x16x32_bf16(bq[nf][kk], a0, ql[0][nf], 0, 0, 0);
        ql[1][nf] = __builtin_amdgcn_mfma_f32_16x16x32_bf16(bq[nf][kk], a1, ql[1][nf], 0, 0, 0);
      }
    }
#pragma unroll
    for (int m = 0; m < 2; ++m) {
      float e0[4], e1[4]; float s8 = 0.f;
#pragma unroll
      for (int r = 0; r < 4; ++r) { e0[r] = __expf(ql[m][0][r]); e1[r] = __expf(ql[m][1][r]); s8 += e0[r] + e1[r]; }
      float s = s8; s += __shfl_xor(s, 16); s += __shfl_xor(s, 32);
      float inv = 1.0f / s;
      qpk[m][0].x = f2bf(e0[0]*inv); qpk[m][0].y = f2bf(e0[1]*inv); qpk[m][0].z = f2bf(e0[2]*inv); qpk[m][0].w = f2bf(e0[3]*inv);
      qpk[m][1].x = f2bf(e1[0]*inv); qpk[m][1].y = f2bf(e1[1]*inv); qpk[m][1].z = f2bf(e1[2]*inv); qpk[m][1].w = f2bf(e1[3]*inv);
    }
  }
  // ---- main loop: iter t stages As(t+1), writes Qs(t), computes P2(t)+P1(t+1) ----
  for (int t = 0; t < 7; ++t) {
    {
      unsigned short* Ab = &As[(t + 1) & 1][0];
      union { ushort4 u4[2]; int4 i4; } pk;
      pk.u4[0].x = f2bf(pa0.x); pk.u4[0].y = f2bf(pa0.y); pk.u4[0].z = f2bf(pa0.z); pk.u4[0].w = f2bf(pa0.w);
      pk.u4[1].x = f2bf(pa1.x); pk.u4[1].y = f2bf(pa1.y); pk.u4[1].z = f2bf(pa1.z); pk.u4[1].w = f2bf(pa1.w);
      *(int4*)(&Ab[aw0]) = pk.i4;
      pk.u4[0].x = f2bf(pa2.x); pk.u4[0].y = f2bf(pa2.y); pk.u4[0].z = f2bf(pa2.z); pk.u4[0].w = f2bf(pa2.w);
      pk.u4[1].x = f2bf(pa3.x); pk.u4[1].y = f2bf(pa3.y); pk.u4[1].z = f2bf(pa3.z); pk.u4[1].w = f2bf(pa3.w);
      *(int4*)(&Ab[aw1]) = pk.i4;
    }
    {
      unsigned short* Qb = &Qs[t & 1][0];
#pragma unroll
      for (int m = 0; m < 2; ++m) {
        int row = m*16 + cl;
#pragma unroll
        for (int nf = 0; nf < 2; ++nf) {
          int slot = qslotbase + nf*2;
          *(ushort4*)(&Qb[row*256 + ((slot ^ (row & 7)) << 3) + (rq & 4)]) = qpk[m][nf];
        }
      }
    }
    if (t < 6) {
      const float* apn = ap + (size_t)(t + 2)*32*256;
      pa0 = *(const float4*)apn;
      pa1 = *(const float4*)(apn + 4);
      pa2 = *(const float4*)(apn + 16*256);
      pa3 = *(const float4*)(apn + 16*256 + 4);
    }
    __syncthreads();
    // P2(t)
    f32x4 oa[2][2] = {};
    {
      unsigned short* Qb = &Qs[t & 1][0];
#pragma unroll
      for (int kk = 0; kk < 8; ++kk) {
        int so = (((kk*4 + fs) ^ (cl & 7)) << 3);
        bf16x8 q0 = *(const bf16x8*)(&Qb[cl*256 + so]);
        bf16x8 q1 = *(const bf16x8*)(&Qb[(16 + cl)*256 + so]);
#pragma unroll
        for (int nf = 0; nf < 2; ++nf) {
          oa[0][nf] = __builtin_amdgcn_mfma_f32_16x16x32_bf16(bw[nf][kk], q0, oa[0][nf], 0, 0, 0);
          oa[1][nf] = __builtin_amdgcn_mfma_f32_16x16x32_bf16(bw[nf][kk], q1, oa[1][nf], 0, 0, 0);
        }
      }
    }
    // P1(t+1) + softmax(t+1)
    {
      unsigned short* Ab = &As[(t + 1) & 1][0];
      f32x4 ql[2][2] = {};
#pragma unroll
      for (int kk = 0; kk < 8; ++kk) {
        int so = (((kk*4 + fs) ^ (cl & 7)) << 3);
        bf16x8 a0 = *(const bf16x8*)(&Ab[cl*256 + so]);
        bf16x8 a1 = *(const bf16x8*)(&Ab[(16 + cl)*256 + so]);
#pragma unroll
        for (int nf = 0; nf < 2; ++nf) {
          ql[0][nf] = __builtin_amdgcn_mfma_f32_16x16x32_bf16(bq[nf][kk], a0, ql[0][nf], 0, 0, 0);
          ql[1][nf] = __builtin_amdgcn_mfma_f32_16x16x32_bf16(bq[nf][kk], a1, ql[1][nf], 0, 0, 0);
        }
      }
#pragma unroll
      for (int m = 0; m < 2; ++m) {
        float e0[4], e1[4]; float s8 = 0.f;
#pragma unroll
        for (int r = 0; r < 4; ++r) { e0[r] = __expf(ql[m][0][r]); e1[r] = __expf(ql[m][1][r]); s8 += e0[r] + e1[r]; }
        float s = s8; s += __shfl_xor(s, 16); s += __shfl_xor(s, 32);
        float inv = 1.0f / s;
        qpk[m][0].x = f2bf(e0[0]*inv); qpk[m][0].y = f2bf(e0[1]*inv); qpk[m][0].z = f2bf(e0[2]*inv); qpk[m][0].w = f2bf(e0[3]*inv);
        qpk[m][1].x = f2bf(e1[0]*inv); qpk[m][1].y = f2bf(e1[1]*inv); qpk[m][1].z = f2bf(e1[2]*inv); qpk[m][1].w = f2bf(e1[3]*inv);
      }
    }
    // out(t): float4 stores (out^T fragment: lane = row n=cl(+16m), 4 consecutive c)
#pragma unroll
    for (int m = 0; m < 2; ++m)
#pragma unroll
      for (int nf = 0; nf < 2; ++nf)
        *(f32x4*)(&out[(rowbase + (size_t)t*32 + m*16 + cl)*256 + wid*32 + nf*16 + rq]) = oa[m][nf];
  }
  // ---- tail: strip 7 ----
  {
    unsigned short* Qb = &Qs[1][0];
#pragma unroll
    for (int m = 0; m < 2; ++m) {
      int row = m*16 + cl;
#pragma unroll
      for (int nf = 0; nf < 2; ++nf) {
        int slot = qslotbase + nf*2;
        *(ushort4*)(&Qb[row*256 + ((slot ^ (row & 7)) << 3) + (rq & 4)]) = qpk[m][nf];
      }
    }
  }
  __syncthreads();
  {
    unsigned short* Qb = &Qs[1][0];
    f32x4 oa[2][2] = {};
#pragma unroll
    for (int kk = 0; kk < 8; ++kk) {
      int so = (((kk*4 + fs) ^ (cl & 7)) << 3);
      bf16x8 q0 = *(const bf16x8*)(&Qb[cl*256 + so]);
      bf16x8 q1 = *(const bf16x8*)(&Qb[(16 + cl)*256 + so]);
#pragma unroll
      for (int nf = 0; nf < 2; ++nf) {
        oa[0][nf] = __builtin_amdgcn_mfma_f32_16x16x32_bf16(bw[nf][kk], q0, oa[0][nf], 0, 0, 0);
        oa[1][nf] = __builtin_amdgcn_mfma_f32_16x16x32_bf16(bw[nf][kk], q1, oa[1][nf], 0, 0, 0);
      }
    }
#pragma unroll
    for (int m = 0; m < 2; ++m)
#pragma unroll
      for (int nf = 0; nf < 2; ++nf)
        *(f32x4*)(&out[(rowbase + (size_t)7*32 + m*16 + cl)*256 + wid*32 + nf*16 + rq]) = oa[m][nf];
  }
}

extern "C" void kernel_launch(void* const* d_in, const int* in_sizes, int n_in,
                              void* d_out, int out_size, void* d_ws, size_t ws_size,
                              hipStream_t stream) {
  const float* x  = (const float*)d_in[0];
  const float* Wq = (const float*)d_in[1];
  const float* Wk = (const float*)d_in[2];
  const float* Wv = (const float*)d_in[3];
  const float* Wo = (const float*)d_in[4];
  float* out = (float*)d_out;

  // ws layout: WkvT (131072 ush) | WqT (65536 ush) | W2t (2097152 ush) | ctxp (512*8*1056 f32)
  unsigned short* WkvT = (unsigned short*)d_ws;
  unsigned short* WqT  = WkvT + 131072;
  unsigned short* W2t  = WqT  + 65536;
  float*          ctxp = (float*)(W2t + 2097152);

  k0_prep <<<768,  256, 0, stream>>>(Wq, Wk, Wv, WqT, WkvT);
  k1p     <<<512,  512, 0, stream>>>(x, WkvT, ctxp);
  k2b_w2  <<<256,  256, 0, stream>>>(ctxp, Wo, W2t);
  k3s     <<<512,  512, 0, stream>>>(x, WqT, W2t, out);
}